// Round 10
// baseline (1808.095 us; speedup 1.0000x reference)
//
#include <hip/hip_runtime.h>
#include <hip/hip_bf16.h>
#include <cstdint>

// GraphQNet: N=20000 nodes, E=320000 edges, B=20 graphs (1000 each), H=256, L=6.
// R10: t_e buffer ELIMINATED. edge_fused computes t = relu(ea@ew1+eb1) on the
// fly (R3's register scheme: ar[4][8] per thread, VALU slice-compute into the
// swizzled sA layout) fused with R9's BK=64 W staging, hv gather prefetch and
// sRed segmented-reduce epilogue. Removes the 164MB/layer te read (R9's FETCH
// was 223MB/dispatch) and the edge_hidden pass. scan_k -> wave-shuffle scan
// (2 barriers/256-chunk instead of 16).

#define NN 20000
#define EE 320000
#define BBG 20
#define PGN 1000
#define HH 256
#define LL 6

typedef short bf16x8 __attribute__((ext_vector_type(8)));
typedef float f32x4 __attribute__((ext_vector_type(4)));

__device__ __forceinline__ void async16(const void* g, void* l) {
  __builtin_amdgcn_global_load_lds(
      (const __attribute__((address_space(1))) unsigned int*)(uintptr_t)g,
      (__attribute__((address_space(3))) unsigned int*)(uintptr_t)l, 16, 0, 0);
}

__device__ __forceinline__ float siluf(float x) { return x / (1.f + __expf(-x)); }

__device__ __forceinline__ unsigned int f2bu(float x) {
  __hip_bfloat16 h = __float2bfloat16(x);
  return (unsigned int)*(unsigned short*)&h;
}

__device__ __forceinline__ float b2f(unsigned short u) {
  unsigned int v = ((unsigned int)u) << 16;
  return *(float*)&v;
}

enum { EPI_SILU = 1, EPI_PLAIN = 2, EPI_TANH = 3 };

// ---------------- node GEMM: C = A[M,256]@W^T (+bias) ----------------
template <int EPI>
__global__ void __launch_bounds__(256, 2) gemm256(
    const __hip_bfloat16* __restrict__ A, const __hip_bfloat16* __restrict__ Wt,
    const float* __restrict__ bias, int M, float* __restrict__ outf,
    __hip_bfloat16* __restrict__ outb) {
  __shared__ __align__(16) __hip_bfloat16 sA[128 * 32];
  __shared__ __align__(16) __hip_bfloat16 sB[128 * 32];

  const int t = threadIdx.x;
  const int wave = t >> 6, lane = t & 63;
  const int row0 = blockIdx.x * 128;
  const int col0 = blockIdx.y * 128;

  const int wrow = (wave >> 1) * 64;
  const int wcol = (wave & 1) * 64;
  const int fr = lane & 15, q = lane >> 4;

  f32x4 zero = {0.f, 0.f, 0.f, 0.f};
  f32x4 acc[4][4];
#pragma unroll
  for (int i = 0; i < 4; i++)
#pragma unroll
    for (int j = 0; j < 4; j++) acc[i][j] = zero;

  const int c1 = t, c2 = t + 256;
  const int lr1 = c1 >> 2, lr2 = c2 >> 2;
  const int q1 = (c1 & 3) ^ ((lr1 >> 1) & 3);
  const int q2 = (c2 & 3) ^ ((lr2 >> 1) & 3);
  int rA1 = row0 + lr1; if (rA1 >= M) rA1 = M - 1;
  int rA2 = row0 + lr2; if (rA2 >= M) rA2 = M - 1;
  const int rB1 = col0 + lr1, rB2 = col0 + lr2;

  for (int k0 = 0; k0 < 256; k0 += 32) {
    async16((const char*)(A + (size_t)rA1 * HH + k0) + q1 * 16,
            (char*)sA + wave * 1024);
    async16((const char*)(A + (size_t)rA2 * HH + k0) + q2 * 16,
            (char*)sA + 4096 + wave * 1024);
    async16((const char*)(Wt + (size_t)rB1 * HH + k0) + q1 * 16,
            (char*)sB + wave * 1024);
    async16((const char*)(Wt + (size_t)rB2 * HH + k0) + q2 * 16,
            (char*)sB + 4096 + wave * 1024);
    __syncthreads();
    bf16x8 af[4], bfr[4];
#pragma unroll
    for (int i = 0; i < 4; i++) {
      const int row = wrow + i * 16 + fr;
      af[i] = *(const bf16x8*)&sA[row * 32 + ((q ^ ((row >> 1) & 3))) * 8];
    }
#pragma unroll
    for (int j = 0; j < 4; j++) {
      const int row = wcol + j * 16 + fr;
      bfr[j] = *(const bf16x8*)&sB[row * 32 + ((q ^ ((row >> 1) & 3))) * 8];
    }
#pragma unroll
    for (int i = 0; i < 4; i++)
#pragma unroll
      for (int j = 0; j < 4; j++)
        acc[i][j] = __builtin_amdgcn_mfma_f32_16x16x32_bf16(af[i], bfr[j],
                                                            acc[i][j], 0, 0, 0);
    __syncthreads();
  }

  // C/D layout: col = lane&15, row = (lane>>4)*4 + reg  [m89-verified]
#pragma unroll
  for (int j = 0; j < 4; j++) {
    const int col = col0 + wcol + j * 16 + fr;
    const float bs = bias[col];
#pragma unroll
    for (int i = 0; i < 4; i++) {
      const int lr0 = wrow + i * 16 + q * 4;
#pragma unroll
      for (int r = 0; r < 4; r++) {
        const int grow = row0 + lr0 + r;
        float v = acc[i][j][r] + bs;
        if (grow < M) {
          if (EPI == EPI_SILU) {
            outb[(size_t)grow * HH + col] = __float2bfloat16(siluf(v));
          } else if (EPI == EPI_PLAIN) {
            outf[(size_t)grow * HH + col] = v;
          } else {
            outb[(size_t)grow * HH + col] = __float2bfloat16(tanhf(v));
          }
        }
      }
    }
  }
}

// ---- node GEMM1 with fp32 A (z): float4 load + cvt + ds_write staging ----
__global__ void __launch_bounds__(256, 2) gemm_silu_f32(
    const float* __restrict__ A, const __hip_bfloat16* __restrict__ Wt,
    const float* __restrict__ bias, int M, __hip_bfloat16* __restrict__ outb) {
  __shared__ __align__(16) __hip_bfloat16 sA[128 * 32];
  __shared__ __align__(16) __hip_bfloat16 sB[128 * 32];

  const int t = threadIdx.x;
  const int wave = t >> 6, lane = t & 63;
  const int row0 = blockIdx.x * 128;
  const int col0 = blockIdx.y * 128;

  const int wrow = (wave >> 1) * 64;
  const int wcol = (wave & 1) * 64;
  const int fr = lane & 15, q = lane >> 4;

  f32x4 zero = {0.f, 0.f, 0.f, 0.f};
  f32x4 acc[4][4];
#pragma unroll
  for (int i = 0; i < 4; i++)
#pragma unroll
    for (int j = 0; j < 4; j++) acc[i][j] = zero;

  const int c1 = t, c2 = t + 256;
  const int lr1 = c1 >> 2, lr2 = c2 >> 2;
  const int q1 = (c1 & 3) ^ ((lr1 >> 1) & 3);
  const int q2 = (c2 & 3) ^ ((lr2 >> 1) & 3);
  int rA1 = row0 + lr1; if (rA1 >= M) rA1 = M - 1;
  int rA2 = row0 + lr2; if (rA2 >= M) rA2 = M - 1;
  const int rB1 = col0 + lr1, rB2 = col0 + lr2;

  for (int k0 = 0; k0 < 256; k0 += 32) {
    async16((const char*)(Wt + (size_t)rB1 * HH + k0) + q1 * 16,
            (char*)sB + wave * 1024);
    async16((const char*)(Wt + (size_t)rB2 * HH + k0) + q2 * 16,
            (char*)sB + 4096 + wave * 1024);
    {
      const float* s1 = A + (size_t)rA1 * HH + k0 + q1 * 8;
      float4 a0 = *(const float4*)s1;
      float4 a1 = *(const float4*)(s1 + 4);
      uint4 u;
      u.x = f2bu(a0.x) | (f2bu(a0.y) << 16);
      u.y = f2bu(a0.z) | (f2bu(a0.w) << 16);
      u.z = f2bu(a1.x) | (f2bu(a1.y) << 16);
      u.w = f2bu(a1.z) | (f2bu(a1.w) << 16);
      *(uint4*)((char*)sA + wave * 1024 + lane * 16) = u;
    }
    {
      const float* s2 = A + (size_t)rA2 * HH + k0 + q2 * 8;
      float4 a0 = *(const float4*)s2;
      float4 a1 = *(const float4*)(s2 + 4);
      uint4 u;
      u.x = f2bu(a0.x) | (f2bu(a0.y) << 16);
      u.y = f2bu(a0.z) | (f2bu(a0.w) << 16);
      u.z = f2bu(a1.x) | (f2bu(a1.y) << 16);
      u.w = f2bu(a1.z) | (f2bu(a1.w) << 16);
      *(uint4*)((char*)sA + 4096 + wave * 1024 + lane * 16) = u;
    }
    __syncthreads();
    bf16x8 af[4], bfr[4];
#pragma unroll
    for (int i = 0; i < 4; i++) {
      const int row = wrow + i * 16 + fr;
      af[i] = *(const bf16x8*)&sA[row * 32 + ((q ^ ((row >> 1) & 3))) * 8];
    }
#pragma unroll
    for (int j = 0; j < 4; j++) {
      const int row = wcol + j * 16 + fr;
      bfr[j] = *(const bf16x8*)&sB[row * 32 + ((q ^ ((row >> 1) & 3))) * 8];
    }
#pragma unroll
    for (int i = 0; i < 4; i++)
#pragma unroll
      for (int j = 0; j < 4; j++)
        acc[i][j] = __builtin_amdgcn_mfma_f32_16x16x32_bf16(af[i], bfr[j],
                                                            acc[i][j], 0, 0, 0);
    __syncthreads();
  }

#pragma unroll
  for (int j = 0; j < 4; j++) {
    const int col = col0 + wcol + j * 16 + fr;
    const float bs = bias[col];
#pragma unroll
    for (int i = 0; i < 4; i++) {
      const int lr0 = wrow + i * 16 + q * 4;
#pragma unroll
      for (int r = 0; r < 4; r++) {
        const int grow = row0 + lr0 + r;
        if (grow < M)
          outb[(size_t)grow * HH + col] =
              __float2bfloat16(siluf(acc[i][j][r] + bs));
      }
    }
  }
}

// ---- node GEMM2 + LayerNorm + residual, fused (row-complete 64x256 tiles) --
__global__ void __launch_bounds__(256, 2) gemm_ln(
    const __hip_bfloat16* __restrict__ A, const __hip_bfloat16* __restrict__ Wt,
    const float* __restrict__ bias, const float* __restrict__ g,
    const float* __restrict__ bbv, float* __restrict__ h,
    float* __restrict__ yzf, __hip_bfloat16* __restrict__ hb) {
  __shared__ __align__(16) char smem[64 * 264 * 2];
  __hip_bfloat16* sA = (__hip_bfloat16*)smem;            // [64][32]
  __hip_bfloat16* sB = (__hip_bfloat16*)(smem + 4096);   // [256][32]
  unsigned short* yb = (unsigned short*)smem;            // [64][264]

  const int t = threadIdx.x;
  const int wave = t >> 6, lane = t & 63;
  const int row0 = blockIdx.x * 64;
  const int wrow = (wave >> 1) * 32;
  const int wcol = (wave & 1) * 128;
  const int fr = lane & 15, q = lane >> 4;

  f32x4 zero = {0.f, 0.f, 0.f, 0.f};
  f32x4 acc[2][8];
#pragma unroll
  for (int i = 0; i < 2; i++)
#pragma unroll
    for (int j = 0; j < 8; j++) acc[i][j] = zero;

  const int lrA = t >> 2;
  const int qA = (t & 3) ^ ((lrA >> 1) & 3);
  int rA = row0 + lrA; if (rA >= NN) rA = NN - 1;
  int qB[4], rB[4];
#pragma unroll
  for (int p = 0; p < 4; p++) {
    const int c = t + p * 256;
    const int lr = c >> 2;
    qB[p] = (c & 3) ^ ((lr >> 1) & 3);
    rB[p] = lr;
  }

  for (int k0 = 0; k0 < 256; k0 += 32) {
    async16((const char*)(A + (size_t)rA * HH + k0) + qA * 16,
            (char*)sA + wave * 1024);
#pragma unroll
    for (int p = 0; p < 4; p++)
      async16((const char*)(Wt + (size_t)rB[p] * HH + k0) + qB[p] * 16,
              (char*)sB + p * 4096 + wave * 1024);
    __syncthreads();
    bf16x8 af[2], bfr[8];
#pragma unroll
    for (int i = 0; i < 2; i++) {
      const int row = wrow + i * 16 + fr;
      af[i] = *(const bf16x8*)&sA[row * 32 + ((q ^ ((row >> 1) & 3))) * 8];
    }
#pragma unroll
    for (int j = 0; j < 8; j++) {
      const int row = wcol + j * 16 + fr;
      bfr[j] = *(const bf16x8*)&sB[row * 32 + ((q ^ ((row >> 1) & 3))) * 8];
    }
#pragma unroll
    for (int i = 0; i < 2; i++)
#pragma unroll
      for (int j = 0; j < 8; j++)
        acc[i][j] = __builtin_amdgcn_mfma_f32_16x16x32_bf16(af[i], bfr[j],
                                                            acc[i][j], 0, 0, 0);
    __syncthreads();
  }

#pragma unroll
  for (int j = 0; j < 8; j++) {
    const int col = wcol + j * 16 + fr;
    const float bs = bias[col];
#pragma unroll
    for (int i = 0; i < 2; i++) {
      const int r0 = wrow + i * 16 + q * 4;
#pragma unroll
      for (int r = 0; r < 4; r++)
        yb[(r0 + r) * 264 + col] = (unsigned short)f2bu(acc[i][j][r] + bs);
    }
  }
  __syncthreads();

  for (int rr = 0; rr < 16; rr++) {
    const int r = wave * 16 + rr;
    const int grow = row0 + r;
    if (grow >= NN) break;
    float v[4];
    float s = 0.f;
#pragma unroll
    for (int i = 0; i < 4; i++) {
      v[i] = b2f(yb[r * 264 + lane + i * 64]);
      s += v[i];
    }
#pragma unroll
    for (int o = 32; o; o >>= 1) s += __shfl_xor(s, o);
    const float mean = s * (1.f / 256.f);
    float var = 0.f;
#pragma unroll
    for (int i = 0; i < 4; i++) { float d = v[i] - mean; var += d * d; }
#pragma unroll
    for (int o = 32; o; o >>= 1) var += __shfl_xor(var, o);
    const float rs = rsqrtf(var * (1.f / 256.f) + 1e-5f);
#pragma unroll
    for (int i = 0; i < 4; i++) {
      const int c = lane + i * 64;
      float ln = (v[i] - mean) * rs * g[c] + bbv[c];
      float si = siluf(ln);
      size_t idx = (size_t)grow * HH + c;
      float nh = h[idx] + si;
      h[idx] = nh;
      yzf[idx] = nh;
      hb[idx] = __float2bfloat16(nh);
    }
  }
}

// -------- fused edge GEMM + segmented reduce (R10: on-the-fly t) -----------
// t = relu(ea[eorig]@ew1+eb1) computed per-block into sA (no t_e buffer);
// U = t@W^T + b ; msg = relu(U + hb[src]); z[dst] += seg-sum(msg).
// grid (2, 2500). BK=64 W staging (2 sub-buffers), hv prefetch, sRed epilogue.
__global__ void __launch_bounds__(256, 3) edge_fused(
    const float* __restrict__ ea, const int* __restrict__ eorig,
    const float* __restrict__ ew1f, const float* __restrict__ eb1f,
    const __hip_bfloat16* __restrict__ Wt, const float* __restrict__ bias,
    const __hip_bfloat16* __restrict__ hbv, const int* __restrict__ srcp,
    const int* __restrict__ dstp, float* __restrict__ z) {
  __shared__ __align__(16) char smem[32768];  // sA 2x8KB | sB 2x8KB
  __shared__ __align__(16) float sew1[8 * 256];
  __shared__ float seb1[256];
  __shared__ int sSrc[128], sDst[128];
  __hip_bfloat16* sA = (__hip_bfloat16*)smem;
  __hip_bfloat16* sB = (__hip_bfloat16*)(smem + 16384);
  unsigned short* sRed = (unsigned short*)smem;  // [64][130] (epilogue union)

  const int t = threadIdx.x;
  const int wave = t >> 6, lane = t & 63;
  const int row0 = blockIdx.y * 128;
  const int col0 = blockIdx.x * 128;

  if (t < 128) { sSrc[t] = srcp[row0 + t]; sDst[t] = dstp[row0 + t]; }
  for (int i = t; i < 8 * 256; i += 256) sew1[i] = ew1f[i];
  seb1[t] = eb1f[t];

  // on-the-fly A: thread owns rows rr..rr+3, k-cols cc..cc+3 per 32-slice
  const int rr = (t >> 3) * 4;
  const int cc = (t & 7) * 4;
  float ar[4][8];
#pragma unroll
  for (int i = 0; i < 4; i++) {
    const int e = eorig[row0 + rr + i];
    const float4 a0 = *(const float4*)&ea[(size_t)e * 8];
    const float4 a1 = *(const float4*)&ea[(size_t)e * 8 + 4];
    ar[i][0] = a0.x; ar[i][1] = a0.y; ar[i][2] = a0.z; ar[i][3] = a0.w;
    ar[i][4] = a1.x; ar[i][5] = a1.y; ar[i][6] = a1.z; ar[i][7] = a1.w;
  }

  const int wrow = (wave >> 1) * 64;
  const int fr = lane & 15, q = lane >> 4;
  const int rc = lane, rb = wave;  // reduce identity
  const int gch = cc >> 3;         // 16B chunk within 32-slice
  const int hby = (cc & 7) * 2;    // byte offset inside chunk

  f32x4 zero = {0.f, 0.f, 0.f, 0.f};
  f32x4 acc[4][4];
#pragma unroll
  for (int i = 0; i < 4; i++)
#pragma unroll
    for (int j = 0; j < 4; j++) acc[i][j] = zero;

  // W staging ids (same as R9)
  const int c1 = t, c2 = t + 256;
  const int lr1 = c1 >> 2, lr2 = c2 >> 2;
  const int q1 = (c1 & 3) ^ ((lr1 >> 1) & 3);
  const int q2 = (c2 & 3) ^ ((lr2 >> 1) & 3);
  const int rB1 = col0 + lr1, rB2 = col0 + lr2;

  float hv[32];

  __syncthreads();  // sew1/seb1/sSrc ready

#pragma unroll
  for (int it = 0; it < 4; it++) {
    const int ka = it * 64, kb = ka + 32;
    async16((const char*)(Wt + (size_t)rB1 * HH + ka) + q1 * 16,
            (char*)sB + wave * 1024);
    async16((const char*)(Wt + (size_t)rB2 * HH + ka) + q2 * 16,
            (char*)sB + 4096 + wave * 1024);
    async16((const char*)(Wt + (size_t)rB1 * HH + kb) + q1 * 16,
            (char*)sB + 8192 + wave * 1024);
    async16((const char*)(Wt + (size_t)rB2 * HH + kb) + q2 * 16,
            (char*)sB + 12288 + wave * 1024);
    // compute two 32-k t-slices into sA halves
#pragma unroll
    for (int half = 0; half < 2; half++) {
      const int k0 = ka + half * 32;
      float tv[4][4];
      const float4 bb = *(const float4*)&seb1[k0 + cc];
#pragma unroll
      for (int i = 0; i < 4; i++) {
        tv[i][0] = bb.x; tv[i][1] = bb.y; tv[i][2] = bb.z; tv[i][3] = bb.w;
      }
#pragma unroll
      for (int j = 0; j < 8; j++) {
        const float4 ww = *(const float4*)&sew1[j * 256 + k0 + cc];
#pragma unroll
        for (int i = 0; i < 4; i++) {
          tv[i][0] += ar[i][j] * ww.x;
          tv[i][1] += ar[i][j] * ww.y;
          tv[i][2] += ar[i][j] * ww.z;
          tv[i][3] += ar[i][j] * ww.w;
        }
      }
#pragma unroll
      for (int i = 0; i < 4; i++) {
        const int r = rr + i;
        const int sl = gch ^ ((r >> 1) & 3);
        ushort4 pk;
        pk.x = (unsigned short)f2bu(tv[i][0] > 0.f ? tv[i][0] : 0.f);
        pk.y = (unsigned short)f2bu(tv[i][1] > 0.f ? tv[i][1] : 0.f);
        pk.z = (unsigned short)f2bu(tv[i][2] > 0.f ? tv[i][2] : 0.f);
        pk.w = (unsigned short)f2bu(tv[i][3] > 0.f ? tv[i][3] : 0.f);
        *(ushort4*)((char*)sA + half * 8192 + r * 64 + sl * 16 + hby) = pk;
      }
    }
    // prefetch 8 bf16 h-gather values (half 0) under the MFMA work
#pragma unroll
    for (int u = 0; u < 8; u++) {
      const int r = it * 8 + u;
      hv[r] = __bfloat162float(hbv[(size_t)sSrc[rb * 32 + r] * HH + col0 + rc]);
    }
    __syncthreads();
#pragma unroll
    for (int half = 0; half < 2; half++) {
      const __hip_bfloat16* pA = sA + half * 4096;
      const __hip_bfloat16* pB = sB + half * 4096;
      bf16x8 af[4], bfr[4];
#pragma unroll
      for (int i = 0; i < 4; i++) {
        const int row = wrow + i * 16 + fr;
        af[i] = *(const bf16x8*)&pA[row * 32 + ((q ^ ((row >> 1) & 3))) * 8];
      }
#pragma unroll
      for (int j = 0; j < 4; j++) {
        const int row = (wave & 1) * 64 + j * 16 + fr;
        bfr[j] = *(const bf16x8*)&pB[row * 32 + ((q ^ ((row >> 1) & 3))) * 8];
      }
#pragma unroll
      for (int i = 0; i < 4; i++)
#pragma unroll
        for (int j = 0; j < 4; j++)
          acc[i][j] = __builtin_amdgcn_mfma_f32_16x16x32_bf16(af[i], bfr[j],
                                                              acc[i][j], 0, 0, 0);
    }
    __syncthreads();
  }

  // epilogue: two 64-col halves staged bf16 in sRed
#pragma unroll
  for (int hf = 0; hf < 2; hf++) {
    if ((wave & 1) == hf) {
#pragma unroll
      for (int j = 0; j < 4; j++) {
        const int cl = j * 16 + fr;
        const float bs = bias[col0 + hf * 64 + cl];
#pragma unroll
        for (int i = 0; i < 4; i++) {
          const int r0 = wrow + i * 16 + q * 4;
          f32x4 v = acc[i][j];
          unsigned int p0 = f2bu(v[0] + bs) | (f2bu(v[1] + bs) << 16);
          unsigned int p1 = f2bu(v[2] + bs) | (f2bu(v[3] + bs) << 16);
          *(unsigned int*)&sRed[cl * 130 + r0] = p0;
          *(unsigned int*)&sRed[cl * 130 + r0 + 2] = p1;
        }
      }
    }
    __syncthreads();
    const int gcol = col0 + hf * 64 + rc;
    float a = 0.f;
    int cur = sDst[rb * 32];
#pragma unroll 4
    for (int r2 = 0; r2 < 32; r2++) {
      const int row = rb * 32 + r2;
      const int d = sDst[row];
      if (d != cur) {
        unsafeAtomicAdd(&z[(size_t)cur * HH + gcol], a);
        a = 0.f;
        cur = d;
      }
      float m = b2f(sRed[rc * 130 + row]) + hv[r2];
      a += m > 0.f ? m : 0.f;
    }
    unsafeAtomicAdd(&z[(size_t)cur * HH + gcol], a);
    if (hf == 0) {
#pragma unroll
      for (int r2 = 0; r2 < 32; r2++)
        hv[r2] = __bfloat162float(
            hbv[(size_t)sSrc[rb * 32 + r2] * HH + col0 + 64 + rc]);
    }
    __syncthreads();
  }
}

// ---- CSR build (per-launch; edge_index is a fixed input) ----
__global__ void __launch_bounds__(256) hist_k(const int* __restrict__ edst,
                                              int* __restrict__ cnt) {
  const int e = blockIdx.x * 256 + threadIdx.x;
  if (e < EE) atomicAdd(&cnt[edst[e]], 1);
}

// wave-shuffle scan: 2 barriers per 256-chunk (was 16)
__global__ void __launch_bounds__(256) scan_k(const int* __restrict__ cnt,
                                              int* __restrict__ rowptr) {
  __shared__ int wsum[4];
  __shared__ int carry;
  const int t = threadIdx.x, wave = t >> 6, lane = t & 63;
  if (t == 0) carry = 0;
  __syncthreads();
  for (int base = 0; base < NN; base += 256) {
    const int idx = base + t;
    int v = (idx < NN) ? cnt[idx] : 0;
    int inc = v;
#pragma unroll
    for (int o = 1; o < 64; o <<= 1) {
      int u = __shfl_up(inc, o);
      if (lane >= o) inc += u;
    }
    if (lane == 63) wsum[wave] = inc;
    __syncthreads();
    int woff = 0;
    for (int w2 = 0; w2 < wave; w2++) woff += wsum[w2];
    if (idx < NN) rowptr[idx] = carry + woff + inc - v;
    const int total = wsum[0] + wsum[1] + wsum[2] + wsum[3];
    __syncthreads();
    if (t == 0) carry += total;
    __syncthreads();
  }
  if (t == 0) rowptr[NN] = carry;
}

// pos = cursor[dst]++ ; eorig[pos]=e ; srcp[pos]=src ; dstp[pos]=dst
__global__ void __launch_bounds__(256) scatter_k(
    const int* __restrict__ esrc, const int* __restrict__ edst,
    int* __restrict__ cursor, int* __restrict__ eorig,
    int* __restrict__ srcp, int* __restrict__ dstp) {
  const int e = blockIdx.x * 256 + threadIdx.x;
  if (e < EE) {
    const int d = edst[e];
    const int pos = atomicAdd(&cursor[d], 1);
    eorig[pos] = e;
    srcp[pos] = esrc[e];
    dstp[pos] = d;
  }
}

// W_l = ew2 @ lin_w[l] (store transposed bf16), b_l = eb2 @ lin_w[l] + lin_b[l]
__global__ void __launch_bounds__(256) fold_edge_w(
    const float* __restrict__ ew2, const float* __restrict__ lin_w,
    const float* __restrict__ eb2, const float* __restrict__ lin_b,
    __hip_bfloat16* __restrict__ Wlt, float* __restrict__ bl) {
  const int l = blockIdx.x >> 8, j = blockIdx.x & 255;
  const int c = threadIdx.x;
  __shared__ float row[256];
  row[c] = ew2[j * 256 + c];
  __syncthreads();
  const float* lw = lin_w + (size_t)l * 65536;
  float a = 0.f;
  for (int k = 0; k < 256; k++) a += row[k] * lw[k * 256 + c];
  Wlt[((size_t)l * 256 + c) * 256 + j] = __float2bfloat16(a);
  if (j == 0) {
    float s = lin_b[l * 256 + c];
    for (int k = 0; k < 256; k++) s += eb2[k] * lw[k * 256 + c];
    bl[l * 256 + c] = s;
  }
}

// transpose+cast fp32 [256,256] -> bf16^T for cw1(6), cw2(6), pa_w1(1)
__global__ void __launch_bounds__(256) tcast_all(
    const float* __restrict__ cw1, const float* __restrict__ cw2,
    const float* __restrict__ paw1, __hip_bfloat16* __restrict__ cw1t,
    __hip_bfloat16* __restrict__ cw2t, __hip_bfloat16* __restrict__ paw1t) {
  const int b = blockIdx.x;
  const float* s;
  __hip_bfloat16* d;
  if (b < 1536) { int l = b >> 8; s = cw1 + (size_t)l * 65536; d = cw1t + (size_t)l * 65536; }
  else if (b < 3072) { int l = (b - 1536) >> 8; s = cw2 + (size_t)l * 65536; d = cw2t + (size_t)l * 65536; }
  else { s = paw1; d = paw1t; }
  const int r = b & 255, c = threadIdx.x;
  d[(size_t)c * 256 + r] = __float2bfloat16(s[(size_t)r * 256 + c]);
}

// h = silu([x, c_scalar] @ in_w + in_b); yzf = h; hb = bf16(h)
__global__ void __launch_bounds__(256) node_init(
    const float* __restrict__ x, const float* __restrict__ cc,
    const int* __restrict__ gid, const int* __restrict__ lid,
    const float* __restrict__ in_w, const float* __restrict__ in_b,
    float* __restrict__ h, float* __restrict__ yzf,
    __hip_bfloat16* __restrict__ hb) {
  __shared__ float w[17 * 256];
  __shared__ float b[256];
  __shared__ float sx[16 * 17];
  const int t = threadIdx.x;
  for (int i = t; i < 17 * 256; i += 256) w[i] = in_w[i];
  b[t] = in_b[t];
  const int n0 = blockIdx.x * 16;
  sx[(t >> 4) * 17 + (t & 15)] = x[(size_t)(n0 + (t >> 4)) * 16 + (t & 15)];
  if (t < 16) {
    int n = n0 + t;
    sx[t * 17 + 16] = cc[gid[n] * PGN + lid[n]];
  }
  __syncthreads();
  for (int e = 0; e < 16; e++) {
    float a = b[t];
#pragma unroll
    for (int j = 0; j < 17; j++) a += sx[e * 17 + j] * w[j * 256 + t];
    float s = siluf(a);
    size_t idx = (size_t)(n0 + e) * HH + t;
    h[idx] = s;
    yzf[idx] = s;
    hb[idx] = __float2bfloat16(s);
  }
}

// scores[n] = s1[n,:] . pa_w2 + pa_b2 ; per-block max -> pmax
__global__ void __launch_bounds__(256) score_k(
    const __hip_bfloat16* __restrict__ s1, const float* __restrict__ pw2,
    const float* __restrict__ pb2, float* __restrict__ scores,
    float* __restrict__ pmax) {
  __shared__ float w2[256];
  __shared__ float bm[4];
  const int t = threadIdx.x, wave = t >> 6, lane = t & 63;
  w2[t] = pw2[t];
  __syncthreads();
  const size_t row = (size_t)blockIdx.x * 4 + wave;
  float a = 0.f;
#pragma unroll
  for (int i = 0; i < 4; i++) {
    int c = lane + i * 64;
    a += __bfloat162float(s1[row * HH + c]) * w2[c];
  }
#pragma unroll
  for (int o = 32; o; o >>= 1) a += __shfl_xor(a, o);
  float sc = a + pb2[0];
  if (lane == 0) { scores[row] = sc; bm[wave] = sc; }
  __syncthreads();
  if (t == 0) pmax[blockIdx.x] = fmaxf(fmaxf(bm[0], bm[1]), fmaxf(bm[2], bm[3]));
}

__global__ void __launch_bounds__(256) gmax_k(const float* __restrict__ pmax,
                                              int n, float* __restrict__ gmax) {
  const int t = threadIdx.x;
  float m = -3.4e38f;
  for (int i = t; i < n; i += 256) m = fmaxf(m, pmax[i]);
#pragma unroll
  for (int o = 32; o; o >>= 1) m = fmaxf(m, __shfl_xor(m, o));
  __shared__ float wm[4];
  if ((t & 63) == 0) wm[t >> 6] = m;
  __syncthreads();
  if (t == 0) gmax[0] = fmaxf(fmaxf(wm[0], wm[1]), fmaxf(wm[2], wm[3]));
}

// en = exp(s - gmax); seg[g] += en ; seg[BBG] = total
__global__ void __launch_bounds__(256) esum_k(
    const float* __restrict__ scores, const int* __restrict__ gid,
    const float* __restrict__ gmax, float* __restrict__ en,
    float* __restrict__ seg) {
  __shared__ float ls[BBG + 1];
  const int t = threadIdx.x;
  if (t < BBG + 1) ls[t] = 0.f;
  __syncthreads();
  const int n = blockIdx.x * 256 + t;
  if (n < NN) {
    float e = __expf(scores[n] - gmax[0]);
    en[n] = e;
    atomicAdd(&ls[gid[n]], e);
    atomicAdd(&ls[BBG], e);
  }
  __syncthreads();
  if (t < BBG + 1) unsafeAtomicAdd(&seg[t], ls[t]);
}

// pooled[g,:] = sum_n en[n]*h[n,:] / (seg[g] + 1e-8*total)
__global__ void __launch_bounds__(256) pooled_k(
    const float* __restrict__ h, const float* __restrict__ en,
    const float* __restrict__ seg, float* __restrict__ pooled) {
  const int g = blockIdx.x / 40, ch = blockIdx.x % 40;
  const int c = threadIdx.x;
  const int n0 = g * PGN + ch * 25;
  float a = 0.f;
  for (int i = 0; i < 25; i++) {
    int n = n0 + i;
    a += en[n] * h[(size_t)n * HH + c];
  }
  const float inv = 1.f / (seg[g] + 1e-8f * seg[BBG]);
  unsafeAtomicAdd(&pooled[g * HH + c], a * inv);
}

// q[b] = silu(pooled[b] @ hw1 + hb1) . hw2 + hb2
__global__ void __launch_bounds__(256) head_k(
    const float* __restrict__ pooled, const float* __restrict__ hw1,
    const float* __restrict__ hb1, const float* __restrict__ hw2,
    const float* __restrict__ hb2, float* __restrict__ qout) {
  const int b = blockIdx.x, c = threadIdx.x;
  __shared__ float p[256];
  __shared__ float wsum[4];
  p[c] = pooled[b * 256 + c];
  __syncthreads();
  float a = hb1[c];
  for (int k = 0; k < 256; k++) a += p[k] * hw1[k * 256 + c];
  float v = siluf(a) * hw2[c];
#pragma unroll
  for (int o = 32; o; o >>= 1) v += __shfl_xor(v, o);
  if ((c & 63) == 0) wsum[c >> 6] = v;
  __syncthreads();
  if (c == 0) qout[b] = wsum[0] + wsum[1] + wsum[2] + wsum[3] + hb2[0];
}

extern "C" void kernel_launch(void* const* d_in, const int* in_sizes, int n_in,
                              void* d_out, int out_size, void* d_ws, size_t ws_size,
                              hipStream_t stream) {
  const float* x = (const float*)d_in[0];
  const float* edge_attr = (const float*)d_in[1];
  const float* cc = (const float*)d_in[2];
  const int* edge_index = (const int*)d_in[3];
  const int* node_gid = (const int*)d_in[4];
  const int* node_lid = (const int*)d_in[5];
  const float* ew1 = (const float*)d_in[6];
  const float* eb1 = (const float*)d_in[7];
  const float* ew2 = (const float*)d_in[8];
  const float* eb2 = (const float*)d_in[9];
  const float* in_w = (const float*)d_in[10];
  const float* in_b = (const float*)d_in[11];
  const float* lin_w = (const float*)d_in[12];
  const float* lin_b = (const float*)d_in[13];
  const float* cw1 = (const float*)d_in[14];
  const float* cb1 = (const float*)d_in[15];
  const float* cw2 = (const float*)d_in[16];
  const float* cb2 = (const float*)d_in[17];
  const float* ln_g = (const float*)d_in[18];
  const float* ln_b = (const float*)d_in[19];
  const float* pa_w1 = (const float*)d_in[20];
  const float* pa_b1 = (const float*)d_in[21];
  const float* pa_w2 = (const float*)d_in[22];
  const float* pa_b2 = (const float*)d_in[23];
  const float* hw1 = (const float*)d_in[24];
  const float* hb1 = (const float*)d_in[25];
  const float* hw2 = (const float*)d_in[26];
  const float* hb2 = (const float*)d_in[27];
  float* qout = (float*)d_out;

  char* w = (char*)d_ws;
  auto alloc = [&](size_t bytes) {
    char* p = w;
    w += (bytes + 255) & ~(size_t)255;
    return p;
  };
  float* h = (float*)alloc((size_t)NN * HH * 4);
  float* yzf = (float*)alloc((size_t)NN * HH * 4);  // z-accumulator
  __hip_bfloat16* hb = (__hip_bfloat16*)alloc((size_t)NN * HH * 2);
  __hip_bfloat16* t2 = (__hip_bfloat16*)alloc((size_t)NN * HH * 2);
  __hip_bfloat16* Wlt = (__hip_bfloat16*)alloc((size_t)LL * HH * HH * 2);
  float* bl = (float*)alloc((size_t)LL * HH * 4);
  __hip_bfloat16* cw1t = (__hip_bfloat16*)alloc((size_t)LL * HH * HH * 2);
  __hip_bfloat16* cw2t = (__hip_bfloat16*)alloc((size_t)LL * HH * HH * 2);
  __hip_bfloat16* paw1t = (__hip_bfloat16*)alloc((size_t)HH * HH * 2);
  float* scores = (float*)alloc((size_t)NN * 4);
  float* pmax = (float*)alloc(5008 * 4);
  float* en = (float*)alloc((size_t)NN * 4);
  float* seg = (float*)alloc((BBG + 1) * 4);
  float* gmax = (float*)alloc(4);
  float* pooled = (float*)alloc((size_t)BBG * HH * 4);
  int* cnt = (int*)alloc((size_t)NN * 4);
  int* rowptr = (int*)alloc((size_t)(NN + 1) * 4);
  int* cursor = (int*)alloc((size_t)NN * 4);
  int* eorig = (int*)alloc((size_t)EE * 4);
  int* srcp = (int*)alloc((size_t)EE * 4);
  int* dstp = (int*)alloc((size_t)EE * 4);

  const int* esrc = edge_index;
  const int* edst = edge_index + EE;

  hipMemsetAsync(cnt, 0, (size_t)NN * 4, stream);
  hipMemsetAsync(seg, 0, (BBG + 1) * 4, stream);
  hipMemsetAsync(pooled, 0, (size_t)BBG * HH * 4, stream);

  // CSR build
  hist_k<<<(EE + 255) / 256, 256, 0, stream>>>(edst, cnt);
  scan_k<<<1, 256, 0, stream>>>(cnt, rowptr);
  hipMemcpyAsync(cursor, rowptr, (size_t)NN * 4, hipMemcpyDeviceToDevice, stream);
  scatter_k<<<(EE + 255) / 256, 256, 0, stream>>>(esrc, edst, cursor, eorig,
                                                  srcp, dstp);

  fold_edge_w<<<LL * 256, 256, 0, stream>>>(ew2, lin_w, eb2, lin_b, Wlt, bl);
  tcast_all<<<3328, 256, 0, stream>>>(cw1, cw2, pa_w1, cw1t, cw2t, paw1t);
  node_init<<<NN / 16, 256, 0, stream>>>(x, cc, node_gid, node_lid, in_w, in_b,
                                         h, yzf, hb);

  dim3 gE(2, EE / 128), gN((NN + 127) / 128, 2);
  const int gLN = (NN + 63) / 64;
  for (int l = 0; l < LL; l++) {
    edge_fused<<<gE, 256, 0, stream>>>(edge_attr, eorig, ew1, eb1,
                                       Wlt + (size_t)l * HH * HH, bl + l * HH,
                                       hb, srcp, dstp, yzf);
    gemm_silu_f32<<<gN, 256, 0, stream>>>(
        yzf, cw1t + (size_t)l * HH * HH, cb1 + l * HH, NN, t2);
    gemm_ln<<<gLN, 256, 0, stream>>>(t2, cw2t + (size_t)l * HH * HH,
                                     cb2 + l * HH, ln_g + l * HH, ln_b + l * HH,
                                     h, yzf, hb);
  }

  gemm256<EPI_TANH><<<gN, 256, 0, stream>>>(hb, paw1t, pa_b1, NN, nullptr, t2);
  score_k<<<NN / 4, 256, 0, stream>>>(t2, pa_w2, pa_b2, scores, pmax);
  gmax_k<<<1, 256, 0, stream>>>(pmax, NN / 4, gmax);
  esum_k<<<(NN + 255) / 256, 256, 0, stream>>>(scores, node_gid, gmax, en, seg);
  pooled_k<<<BBG * 40, 256, 0, stream>>>(h, en, seg, pooled);
  head_k<<<BBG, 256, 0, stream>>>(pooled, hw1, hb1, hw2, hb2, qout);
}

// Round 11
// 1206.792 us; speedup vs baseline: 1.4983x; 1.4983x over previous
//
#include <hip/hip_runtime.h>
#include <hip/hip_bf16.h>
#include <cstdint>

// GraphQNet: N=20000 nodes, E=320000 edges, B=20 graphs (1000 each), H=256, L=6.
// R11: revert to R9 base (R10's on-the-fly recompute spilled ~150MB/dispatch of
// scratch: WRITE 29->275MB). Changes vs R9:
//  (1) edge_fused: drop long-lived hv[32] (was pinning 3 waves/SIMD at 148
//      unified regs); epilogue gathers in 8-reg chunks; launch_bounds(256,4).
//  (2) gemm_silu_f32 + gemm_ln fused into mlp_ln: t2 stays in LDS (bf16
//      [64][264]), no HBM round-trip, 6 fewer launches.
//  (3) keep R10's wave-shuffle scan_k.

#define NN 20000
#define EE 320000
#define BBG 20
#define PGN 1000
#define HH 256
#define LL 6

typedef short bf16x8 __attribute__((ext_vector_type(8)));
typedef float f32x4 __attribute__((ext_vector_type(4)));

__device__ __forceinline__ void async16(const void* g, void* l) {
  __builtin_amdgcn_global_load_lds(
      (const __attribute__((address_space(1))) unsigned int*)(uintptr_t)g,
      (__attribute__((address_space(3))) unsigned int*)(uintptr_t)l, 16, 0, 0);
}

__device__ __forceinline__ float siluf(float x) { return x / (1.f + __expf(-x)); }

__device__ __forceinline__ unsigned int f2bu(float x) {
  __hip_bfloat16 h = __float2bfloat16(x);
  return (unsigned int)*(unsigned short*)&h;
}

__device__ __forceinline__ float b2f(unsigned short u) {
  unsigned int v = ((unsigned int)u) << 16;
  return *(float*)&v;
}

enum { EPI_SILU = 1, EPI_PLAIN = 2, EPI_TANH = 3 };

// ---------------- node GEMM: C = A[M,256]@W^T (+bias) ----------------
template <int EPI>
__global__ void __launch_bounds__(256, 2) gemm256(
    const __hip_bfloat16* __restrict__ A, const __hip_bfloat16* __restrict__ Wt,
    const float* __restrict__ bias, int M, float* __restrict__ outf,
    __hip_bfloat16* __restrict__ outb) {
  __shared__ __align__(16) __hip_bfloat16 sA[128 * 32];
  __shared__ __align__(16) __hip_bfloat16 sB[128 * 32];

  const int t = threadIdx.x;
  const int wave = t >> 6, lane = t & 63;
  const int row0 = blockIdx.x * 128;
  const int col0 = blockIdx.y * 128;

  const int wrow = (wave >> 1) * 64;
  const int wcol = (wave & 1) * 64;
  const int fr = lane & 15, q = lane >> 4;

  f32x4 zero = {0.f, 0.f, 0.f, 0.f};
  f32x4 acc[4][4];
#pragma unroll
  for (int i = 0; i < 4; i++)
#pragma unroll
    for (int j = 0; j < 4; j++) acc[i][j] = zero;

  const int c1 = t, c2 = t + 256;
  const int lr1 = c1 >> 2, lr2 = c2 >> 2;
  const int q1 = (c1 & 3) ^ ((lr1 >> 1) & 3);
  const int q2 = (c2 & 3) ^ ((lr2 >> 1) & 3);
  int rA1 = row0 + lr1; if (rA1 >= M) rA1 = M - 1;
  int rA2 = row0 + lr2; if (rA2 >= M) rA2 = M - 1;
  const int rB1 = col0 + lr1, rB2 = col0 + lr2;

  for (int k0 = 0; k0 < 256; k0 += 32) {
    async16((const char*)(A + (size_t)rA1 * HH + k0) + q1 * 16,
            (char*)sA + wave * 1024);
    async16((const char*)(A + (size_t)rA2 * HH + k0) + q2 * 16,
            (char*)sA + 4096 + wave * 1024);
    async16((const char*)(Wt + (size_t)rB1 * HH + k0) + q1 * 16,
            (char*)sB + wave * 1024);
    async16((const char*)(Wt + (size_t)rB2 * HH + k0) + q2 * 16,
            (char*)sB + 4096 + wave * 1024);
    __syncthreads();
    bf16x8 af[4], bfr[4];
#pragma unroll
    for (int i = 0; i < 4; i++) {
      const int row = wrow + i * 16 + fr;
      af[i] = *(const bf16x8*)&sA[row * 32 + ((q ^ ((row >> 1) & 3))) * 8];
    }
#pragma unroll
    for (int j = 0; j < 4; j++) {
      const int row = wcol + j * 16 + fr;
      bfr[j] = *(const bf16x8*)&sB[row * 32 + ((q ^ ((row >> 1) & 3))) * 8];
    }
#pragma unroll
    for (int i = 0; i < 4; i++)
#pragma unroll
      for (int j = 0; j < 4; j++)
        acc[i][j] = __builtin_amdgcn_mfma_f32_16x16x32_bf16(af[i], bfr[j],
                                                            acc[i][j], 0, 0, 0);
    __syncthreads();
  }

  // C/D layout: col = lane&15, row = (lane>>4)*4 + reg  [m89-verified]
#pragma unroll
  for (int j = 0; j < 4; j++) {
    const int col = col0 + wcol + j * 16 + fr;
    const float bs = bias[col];
#pragma unroll
    for (int i = 0; i < 4; i++) {
      const int lr0 = wrow + i * 16 + q * 4;
#pragma unroll
      for (int r = 0; r < 4; r++) {
        const int grow = row0 + lr0 + r;
        float v = acc[i][j][r] + bs;
        if (grow < M) {
          if (EPI == EPI_SILU) {
            outb[(size_t)grow * HH + col] = __float2bfloat16(siluf(v));
          } else if (EPI == EPI_PLAIN) {
            outf[(size_t)grow * HH + col] = v;
          } else {
            outb[(size_t)grow * HH + col] = __float2bfloat16(tanhf(v));
          }
        }
      }
    }
  }
}

// ---- fused node MLP + LN + residual (64 rows/block, full 256 cols) ----
// t2 = silu(z@W1^T + b1) staged bf16 in LDS; y = t2@W2^T + b2 staged in LDS;
// h += silu(LN(y)); yzf = h; hb = bf16(h). t2/y never touch HBM.
__global__ void __launch_bounds__(256, 2) mlp_ln(
    const float* __restrict__ z, const __hip_bfloat16* __restrict__ W1t,
    const float* __restrict__ b1, const __hip_bfloat16* __restrict__ W2t,
    const float* __restrict__ b2, const float* __restrict__ g,
    const float* __restrict__ bbv, float* __restrict__ h,
    float* __restrict__ yzf, __hip_bfloat16* __restrict__ hb) {
  __shared__ __align__(16) char smem[20480 + 64 * 264 * 2];
  __hip_bfloat16* sA = (__hip_bfloat16*)smem;             // [64][32]  4KB
  __hip_bfloat16* sB = (__hip_bfloat16*)(smem + 4096);    // [256][32] 16KB
  unsigned short* sT = (unsigned short*)(smem + 20480);   // [64][264] bf16

  const int t = threadIdx.x;
  const int wave = t >> 6, lane = t & 63;
  const int row0 = blockIdx.x * 64;
  const int fr = lane & 15, q = lane >> 4;
  const int wr = wave * 16;  // wave's local row base

  // A staging (phase 1, fp32 z): 256 chunks = [64 rows][4 slots]; chunk t.
  const int lrA = t >> 2;
  const int qA = (t & 3) ^ ((lrA >> 1) & 3);
  int rA = row0 + lrA; if (rA >= NN) rA = NN - 1;
  // B staging: 1024 chunks = [256 rows][4 slots]; chunks t + p*256.
  int qB[4], rB[4];
#pragma unroll
  for (int p = 0; p < 4; p++) {
    const int c = t + p * 256;
    const int lr = c >> 2;
    qB[p] = (c & 3) ^ ((lr >> 1) & 3);
    rB[p] = lr;
  }

  f32x4 zero = {0.f, 0.f, 0.f, 0.f};
  f32x4 acc[16];
#pragma unroll
  for (int j = 0; j < 16; j++) acc[j] = zero;

  // -------- phase 1: z @ W1^T --------
  for (int k0 = 0; k0 < 256; k0 += 32) {
    {
      const float* s1 = z + (size_t)rA * HH + k0 + qA * 8;
      float4 a0 = *(const float4*)s1;
      float4 a1 = *(const float4*)(s1 + 4);
      uint4 u;
      u.x = f2bu(a0.x) | (f2bu(a0.y) << 16);
      u.y = f2bu(a0.z) | (f2bu(a0.w) << 16);
      u.z = f2bu(a1.x) | (f2bu(a1.y) << 16);
      u.w = f2bu(a1.z) | (f2bu(a1.w) << 16);
      *(uint4*)((char*)sA + t * 16) = u;
    }
#pragma unroll
    for (int p = 0; p < 4; p++)
      async16((const char*)(W1t + (size_t)rB[p] * HH + k0) + qB[p] * 16,
              (char*)sB + p * 4096 + wave * 1024);
    __syncthreads();
    bf16x8 af;
    {
      const int row = wr + fr;
      af = *(const bf16x8*)&sA[row * 32 + ((q ^ ((row >> 1) & 3))) * 8];
    }
#pragma unroll
    for (int j = 0; j < 16; j++) {
      const int row = j * 16 + fr;
      bf16x8 bfr = *(const bf16x8*)&sB[row * 32 + ((q ^ ((row >> 1) & 3))) * 8];
      acc[j] = __builtin_amdgcn_mfma_f32_16x16x32_bf16(af, bfr, acc[j], 0, 0, 0);
    }
    __syncthreads();
  }
  // t2 = silu(acc + b1) -> sT  (C layout: col=fr per tile, row=q*4+r)
#pragma unroll
  for (int j = 0; j < 16; j++) {
    const int col = j * 16 + fr;
    const float bs = b1[col];
    const int r0 = wr + q * 4;
#pragma unroll
    for (int r = 0; r < 4; r++)
      sT[(r0 + r) * 264 + col] =
          (unsigned short)f2bu(siluf(acc[j][r] + bs));
  }
#pragma unroll
  for (int j = 0; j < 16; j++) acc[j] = zero;

  // -------- phase 2: t2 @ W2^T (A from sT) --------
  for (int k0 = 0; k0 < 256; k0 += 32) {
#pragma unroll
    for (int p = 0; p < 4; p++)
      async16((const char*)(W2t + (size_t)rB[p] * HH + k0) + qB[p] * 16,
              (char*)sB + p * 4096 + wave * 1024);
    __syncthreads();  // also orders sT writes before first read
    bf16x8 af = *(const bf16x8*)&sT[(wr + fr) * 264 + k0 + q * 8];
#pragma unroll
    for (int j = 0; j < 16; j++) {
      const int row = j * 16 + fr;
      bf16x8 bfr = *(const bf16x8*)&sB[row * 32 + ((q ^ ((row >> 1) & 3))) * 8];
      acc[j] = __builtin_amdgcn_mfma_f32_16x16x32_bf16(af, bfr, acc[j], 0, 0, 0);
    }
    __syncthreads();
  }
  // y = acc + b2 -> sT (overwrite)
#pragma unroll
  for (int j = 0; j < 16; j++) {
    const int col = j * 16 + fr;
    const float bs = b2[col];
    const int r0 = wr + q * 4;
#pragma unroll
    for (int r = 0; r < 4; r++)
      sT[(r0 + r) * 264 + col] = (unsigned short)f2bu(acc[j][r] + bs);
  }
  __syncthreads();

  // LN + silu + residual: wave handles rows wr..wr+15
  for (int rr = 0; rr < 16; rr++) {
    const int r = wr + rr;
    const int grow = row0 + r;
    if (grow >= NN) break;
    float v[4];
    float s = 0.f;
#pragma unroll
    for (int i = 0; i < 4; i++) {
      v[i] = b2f(sT[r * 264 + lane + i * 64]);
      s += v[i];
    }
#pragma unroll
    for (int o = 32; o; o >>= 1) s += __shfl_xor(s, o);
    const float mean = s * (1.f / 256.f);
    float var = 0.f;
#pragma unroll
    for (int i = 0; i < 4; i++) { float d = v[i] - mean; var += d * d; }
#pragma unroll
    for (int o = 32; o; o >>= 1) var += __shfl_xor(var, o);
    const float rs = rsqrtf(var * (1.f / 256.f) + 1e-5f);
#pragma unroll
    for (int i = 0; i < 4; i++) {
      const int c = lane + i * 64;
      float ln = (v[i] - mean) * rs * g[c] + bbv[c];
      float si = siluf(ln);
      size_t idx = (size_t)grow * HH + c;
      float nh = h[idx] + si;
      h[idx] = nh;
      yzf[idx] = nh;
      hb[idx] = __float2bfloat16(nh);
    }
  }
}

// -------- fused edge GEMM + segmented reduce (R11: 4 waves/SIMD) ------------
// U = t_e@W^T + b ; msg = relu(U + hb[src]); z[dst] += seg-sum(msg).
// grid (2, 2500). BK=64 (2 sub-buffers/barrier). Gathers done in the epilogue
// in 8-reg chunks (no long-lived hv[32]) so unified regs fit 4 waves/SIMD.
__global__ void __launch_bounds__(256, 4) edge_fused(
    const __hip_bfloat16* __restrict__ te, const __hip_bfloat16* __restrict__ Wt,
    const float* __restrict__ bias, const __hip_bfloat16* __restrict__ hbv,
    const int* __restrict__ srcp, const int* __restrict__ dstp,
    float* __restrict__ z) {
  __shared__ __align__(16) char smem[32768];  // sA 2x8KB | sB 2x8KB
  __shared__ int sSrc[128], sDst[128];
  __hip_bfloat16* sA = (__hip_bfloat16*)smem;
  __hip_bfloat16* sB = (__hip_bfloat16*)(smem + 16384);
  unsigned short* sRed = (unsigned short*)smem;  // [64][130] (epilogue union)

  const int t = threadIdx.x;
  const int wave = t >> 6, lane = t & 63;
  const int row0 = blockIdx.y * 128;
  const int col0 = blockIdx.x * 128;

  if (t < 128) { sSrc[t] = srcp[row0 + t]; sDst[t] = dstp[row0 + t]; }
  __syncthreads();

  const int wrow = (wave >> 1) * 64;
  const int fr = lane & 15, q = lane >> 4;
  const int rc = lane, rb = wave;  // reduce identity

  f32x4 zero = {0.f, 0.f, 0.f, 0.f};
  f32x4 acc[4][4];
#pragma unroll
  for (int i = 0; i < 4; i++)
#pragma unroll
    for (int j = 0; j < 4; j++) acc[i][j] = zero;

  const int c1 = t, c2 = t + 256;
  const int lr1 = c1 >> 2, lr2 = c2 >> 2;
  const int q1 = (c1 & 3) ^ ((lr1 >> 1) & 3);
  const int q2 = (c2 & 3) ^ ((lr2 >> 1) & 3);
  const int rA1 = row0 + lr1, rA2 = row0 + lr2;
  const int rB1 = col0 + lr1, rB2 = col0 + lr2;

#pragma unroll
  for (int it = 0; it < 4; it++) {
    const int ka = it * 64, kb = ka + 32;
    async16((const char*)(te + (size_t)rA1 * HH + ka) + q1 * 16,
            (char*)sA + wave * 1024);
    async16((const char*)(te + (size_t)rA2 * HH + ka) + q2 * 16,
            (char*)sA + 4096 + wave * 1024);
    async16((const char*)(te + (size_t)rA1 * HH + kb) + q1 * 16,
            (char*)sA + 8192 + wave * 1024);
    async16((const char*)(te + (size_t)rA2 * HH + kb) + q2 * 16,
            (char*)sA + 12288 + wave * 1024);
    async16((const char*)(Wt + (size_t)rB1 * HH + ka) + q1 * 16,
            (char*)sB + wave * 1024);
    async16((const char*)(Wt + (size_t)rB2 * HH + ka) + q2 * 16,
            (char*)sB + 4096 + wave * 1024);
    async16((const char*)(Wt + (size_t)rB1 * HH + kb) + q1 * 16,
            (char*)sB + 8192 + wave * 1024);
    async16((const char*)(Wt + (size_t)rB2 * HH + kb) + q2 * 16,
            (char*)sB + 12288 + wave * 1024);
    __syncthreads();
#pragma unroll
    for (int half = 0; half < 2; half++) {
      const __hip_bfloat16* pA = sA + half * 4096;
      const __hip_bfloat16* pB = sB + half * 4096;
      bf16x8 af[4], bfr[4];
#pragma unroll
      for (int i = 0; i < 4; i++) {
        const int row = wrow + i * 16 + fr;
        af[i] = *(const bf16x8*)&pA[row * 32 + ((q ^ ((row >> 1) & 3))) * 8];
      }
#pragma unroll
      for (int j = 0; j < 4; j++) {
        const int row = (wave & 1) * 64 + j * 16 + fr;
        bfr[j] = *(const bf16x8*)&pB[row * 32 + ((q ^ ((row >> 1) & 3))) * 8];
      }
#pragma unroll
      for (int i = 0; i < 4; i++)
#pragma unroll
        for (int j = 0; j < 4; j++)
          acc[i][j] = __builtin_amdgcn_mfma_f32_16x16x32_bf16(af[i], bfr[j],
                                                              acc[i][j], 0, 0, 0);
    }
    __syncthreads();
  }

  // epilogue: two 64-col halves staged bf16 in sRed; gathers in 8-reg chunks
#pragma unroll
  for (int hf = 0; hf < 2; hf++) {
    if ((wave & 1) == hf) {
#pragma unroll
      for (int j = 0; j < 4; j++) {
        const int cl = j * 16 + fr;
        const float bs = bias[col0 + hf * 64 + cl];
#pragma unroll
        for (int i = 0; i < 4; i++) {
          const int r0 = wrow + i * 16 + q * 4;
          f32x4 v = acc[i][j];
          unsigned int p0 = f2bu(v[0] + bs) | (f2bu(v[1] + bs) << 16);
          unsigned int p1 = f2bu(v[2] + bs) | (f2bu(v[3] + bs) << 16);
          *(unsigned int*)&sRed[cl * 130 + r0] = p0;
          *(unsigned int*)&sRed[cl * 130 + r0 + 2] = p1;
        }
      }
    }
    __syncthreads();
    const int gcol = col0 + hf * 64 + rc;
    float a = 0.f;
    int cur = sDst[rb * 32];
    for (int ch = 0; ch < 4; ch++) {
      float hv8[8];
#pragma unroll
      for (int u = 0; u < 8; u++)
        hv8[u] = __bfloat162float(
            hbv[(size_t)sSrc[rb * 32 + ch * 8 + u] * HH + gcol]);
#pragma unroll
      for (int u = 0; u < 8; u++) {
        const int row = rb * 32 + ch * 8 + u;
        const int d = sDst[row];
        if (d != cur) {
          unsafeAtomicAdd(&z[(size_t)cur * HH + gcol], a);
          a = 0.f;
          cur = d;
        }
        float m = b2f(sRed[rc * 130 + row]) + hv8[u];
        a += m > 0.f ? m : 0.f;
      }
    }
    unsafeAtomicAdd(&z[(size_t)cur * HH + gcol], a);
    __syncthreads();
  }
}

// ---- CSR build (per-launch; edge_index is a fixed input) ----
__global__ void __launch_bounds__(256) hist_k(const int* __restrict__ edst,
                                              int* __restrict__ cnt) {
  const int e = blockIdx.x * 256 + threadIdx.x;
  if (e < EE) atomicAdd(&cnt[edst[e]], 1);
}

// wave-shuffle scan: 2 barriers per 256-chunk
__global__ void __launch_bounds__(256) scan_k(const int* __restrict__ cnt,
                                              int* __restrict__ rowptr) {
  __shared__ int wsum[4];
  __shared__ int carry;
  const int t = threadIdx.x, wave = t >> 6, lane = t & 63;
  if (t == 0) carry = 0;
  __syncthreads();
  for (int base = 0; base < NN; base += 256) {
    const int idx = base + t;
    int v = (idx < NN) ? cnt[idx] : 0;
    int inc = v;
#pragma unroll
    for (int o = 1; o < 64; o <<= 1) {
      int u = __shfl_up(inc, o);
      if (lane >= o) inc += u;
    }
    if (lane == 63) wsum[wave] = inc;
    __syncthreads();
    int woff = 0;
    for (int w2 = 0; w2 < wave; w2++) woff += wsum[w2];
    if (idx < NN) rowptr[idx] = carry + woff + inc - v;
    const int total = wsum[0] + wsum[1] + wsum[2] + wsum[3];
    __syncthreads();
    if (t == 0) carry += total;
    __syncthreads();
  }
  if (t == 0) rowptr[NN] = carry;
}

__global__ void __launch_bounds__(256) scatter_k(
    const int* __restrict__ esrc, const int* __restrict__ edst,
    int* __restrict__ cursor, int* __restrict__ posof,
    int* __restrict__ srcp, int* __restrict__ dstp) {
  const int e = blockIdx.x * 256 + threadIdx.x;
  if (e < EE) {
    const int d = edst[e];
    const int pos = atomicAdd(&cursor[d], 1);
    posof[e] = pos;
    srcp[pos] = esrc[e];
    dstp[pos] = d;
  }
}

// t_e[posof[e]] = relu(ea[e] @ ew1 + eb1) -> bf16 (dst-sorted order)
__global__ void __launch_bounds__(256) edge_hidden(
    const float* __restrict__ ea, const float* __restrict__ ew1,
    const float* __restrict__ eb1, const int* __restrict__ posof,
    __hip_bfloat16* __restrict__ tout) {
  __shared__ float w[8 * 256];
  __shared__ float b[256];
  __shared__ float sea[16 * 8];
  __shared__ int spos[16];
  const int t = threadIdx.x;
  for (int i = t; i < 8 * 256; i += 256) w[i] = ew1[i];
  b[t] = eb1[t];
  const int e0 = blockIdx.x * 16;
  if (t < 128) sea[t] = ea[(size_t)e0 * 8 + t];
  if (t < 16) spos[t] = posof[e0 + t];
  __syncthreads();
  for (int e = 0; e < 16; e++) {
    float a = b[t];
#pragma unroll
    for (int j = 0; j < 8; j++) a += sea[e * 8 + j] * w[j * 256 + t];
    tout[(size_t)spos[e] * HH + t] = __float2bfloat16(a > 0.f ? a : 0.f);
  }
}

// W_l = ew2 @ lin_w[l] (store transposed bf16), b_l = eb2 @ lin_w[l] + lin_b[l]
__global__ void __launch_bounds__(256) fold_edge_w(
    const float* __restrict__ ew2, const float* __restrict__ lin_w,
    const float* __restrict__ eb2, const float* __restrict__ lin_b,
    __hip_bfloat16* __restrict__ Wlt, float* __restrict__ bl) {
  const int l = blockIdx.x >> 8, j = blockIdx.x & 255;
  const int c = threadIdx.x;
  __shared__ float row[256];
  row[c] = ew2[j * 256 + c];
  __syncthreads();
  const float* lw = lin_w + (size_t)l * 65536;
  float a = 0.f;
  for (int k = 0; k < 256; k++) a += row[k] * lw[k * 256 + c];
  Wlt[((size_t)l * 256 + c) * 256 + j] = __float2bfloat16(a);
  if (j == 0) {
    float s = lin_b[l * 256 + c];
    for (int k = 0; k < 256; k++) s += eb2[k] * lw[k * 256 + c];
    bl[l * 256 + c] = s;
  }
}

// transpose+cast fp32 [256,256] -> bf16^T for cw1(6), cw2(6), pa_w1(1)
__global__ void __launch_bounds__(256) tcast_all(
    const float* __restrict__ cw1, const float* __restrict__ cw2,
    const float* __restrict__ paw1, __hip_bfloat16* __restrict__ cw1t,
    __hip_bfloat16* __restrict__ cw2t, __hip_bfloat16* __restrict__ paw1t) {
  const int b = blockIdx.x;
  const float* s;
  __hip_bfloat16* d;
  if (b < 1536) { int l = b >> 8; s = cw1 + (size_t)l * 65536; d = cw1t + (size_t)l * 65536; }
  else if (b < 3072) { int l = (b - 1536) >> 8; s = cw2 + (size_t)l * 65536; d = cw2t + (size_t)l * 65536; }
  else { s = paw1; d = paw1t; }
  const int r = b & 255, c = threadIdx.x;
  d[(size_t)c * 256 + r] = __float2bfloat16(s[(size_t)r * 256 + c]);
}

// h = silu([x, c_scalar] @ in_w + in_b); yzf = h; hb = bf16(h)
__global__ void __launch_bounds__(256) node_init(
    const float* __restrict__ x, const float* __restrict__ cc,
    const int* __restrict__ gid, const int* __restrict__ lid,
    const float* __restrict__ in_w, const float* __restrict__ in_b,
    float* __restrict__ h, float* __restrict__ yzf,
    __hip_bfloat16* __restrict__ hb) {
  __shared__ float w[17 * 256];
  __shared__ float b[256];
  __shared__ float sx[16 * 17];
  const int t = threadIdx.x;
  for (int i = t; i < 17 * 256; i += 256) w[i] = in_w[i];
  b[t] = in_b[t];
  const int n0 = blockIdx.x * 16;
  sx[(t >> 4) * 17 + (t & 15)] = x[(size_t)(n0 + (t >> 4)) * 16 + (t & 15)];
  if (t < 16) {
    int n = n0 + t;
    sx[t * 17 + 16] = cc[gid[n] * PGN + lid[n]];
  }
  __syncthreads();
  for (int e = 0; e < 16; e++) {
    float a = b[t];
#pragma unroll
    for (int j = 0; j < 17; j++) a += sx[e * 17 + j] * w[j * 256 + t];
    float s = siluf(a);
    size_t idx = (size_t)(n0 + e) * HH + t;
    h[idx] = s;
    yzf[idx] = s;
    hb[idx] = __float2bfloat16(s);
  }
}

// scores[n] = s1[n,:] . pa_w2 + pa_b2 ; per-block max -> pmax
__global__ void __launch_bounds__(256) score_k(
    const __hip_bfloat16* __restrict__ s1, const float* __restrict__ pw2,
    const float* __restrict__ pb2, float* __restrict__ scores,
    float* __restrict__ pmax) {
  __shared__ float w2[256];
  __shared__ float bm[4];
  const int t = threadIdx.x, wave = t >> 6, lane = t & 63;
  w2[t] = pw2[t];
  __syncthreads();
  const size_t row = (size_t)blockIdx.x * 4 + wave;
  float a = 0.f;
#pragma unroll
  for (int i = 0; i < 4; i++) {
    int c = lane + i * 64;
    a += __bfloat162float(s1[row * HH + c]) * w2[c];
  }
#pragma unroll
  for (int o = 32; o; o >>= 1) a += __shfl_xor(a, o);
  float sc = a + pb2[0];
  if (lane == 0) { scores[row] = sc; bm[wave] = sc; }
  __syncthreads();
  if (t == 0) pmax[blockIdx.x] = fmaxf(fmaxf(bm[0], bm[1]), fmaxf(bm[2], bm[3]));
}

__global__ void __launch_bounds__(256) gmax_k(const float* __restrict__ pmax,
                                              int n, float* __restrict__ gmax) {
  const int t = threadIdx.x;
  float m = -3.4e38f;
  for (int i = t; i < n; i += 256) m = fmaxf(m, pmax[i]);
#pragma unroll
  for (int o = 32; o; o >>= 1) m = fmaxf(m, __shfl_xor(m, o));
  __shared__ float wm[4];
  if ((t & 63) == 0) wm[t >> 6] = m;
  __syncthreads();
  if (t == 0) gmax[0] = fmaxf(fmaxf(wm[0], wm[1]), fmaxf(wm[2], wm[3]));
}

// en = exp(s - gmax); seg[g] += en ; seg[BBG] = total
__global__ void __launch_bounds__(256) esum_k(
    const float* __restrict__ scores, const int* __restrict__ gid,
    const float* __restrict__ gmax, float* __restrict__ en,
    float* __restrict__ seg) {
  __shared__ float ls[BBG + 1];
  const int t = threadIdx.x;
  if (t < BBG + 1) ls[t] = 0.f;
  __syncthreads();
  const int n = blockIdx.x * 256 + t;
  if (n < NN) {
    float e = __expf(scores[n] - gmax[0]);
    en[n] = e;
    atomicAdd(&ls[gid[n]], e);
    atomicAdd(&ls[BBG], e);
  }
  __syncthreads();
  if (t < BBG + 1) unsafeAtomicAdd(&seg[t], ls[t]);
}

// pooled[g,:] = sum_n en[n]*h[n,:] / (seg[g] + 1e-8*total)
__global__ void __launch_bounds__(256) pooled_k(
    const float* __restrict__ h, const float* __restrict__ en,
    const float* __restrict__ seg, float* __restrict__ pooled) {
  const int g = blockIdx.x / 40, ch = blockIdx.x % 40;
  const int c = threadIdx.x;
  const int n0 = g * PGN + ch * 25;
  float a = 0.f;
  for (int i = 0; i < 25; i++) {
    int n = n0 + i;
    a += en[n] * h[(size_t)n * HH + c];
  }
  const float inv = 1.f / (seg[g] + 1e-8f * seg[BBG]);
  unsafeAtomicAdd(&pooled[g * HH + c], a * inv);
}

// q[b] = silu(pooled[b] @ hw1 + hb1) . hw2 + hb2
__global__ void __launch_bounds__(256) head_k(
    const float* __restrict__ pooled, const float* __restrict__ hw1,
    const float* __restrict__ hb1, const float* __restrict__ hw2,
    const float* __restrict__ hb2, float* __restrict__ qout) {
  const int b = blockIdx.x, c = threadIdx.x;
  __shared__ float p[256];
  __shared__ float wsum[4];
  p[c] = pooled[b * 256 + c];
  __syncthreads();
  float a = hb1[c];
  for (int k = 0; k < 256; k++) a += p[k] * hw1[k * 256 + c];
  float v = siluf(a) * hw2[c];
#pragma unroll
  for (int o = 32; o; o >>= 1) v += __shfl_xor(v, o);
  if ((c & 63) == 0) wsum[c >> 6] = v;
  __syncthreads();
  if (c == 0) qout[b] = wsum[0] + wsum[1] + wsum[2] + wsum[3] + hb2[0];
}

extern "C" void kernel_launch(void* const* d_in, const int* in_sizes, int n_in,
                              void* d_out, int out_size, void* d_ws, size_t ws_size,
                              hipStream_t stream) {
  const float* x = (const float*)d_in[0];
  const float* edge_attr = (const float*)d_in[1];
  const float* cc = (const float*)d_in[2];
  const int* edge_index = (const int*)d_in[3];
  const int* node_gid = (const int*)d_in[4];
  const int* node_lid = (const int*)d_in[5];
  const float* ew1 = (const float*)d_in[6];
  const float* eb1 = (const float*)d_in[7];
  const float* ew2 = (const float*)d_in[8];
  const float* eb2 = (const float*)d_in[9];
  const float* in_w = (const float*)d_in[10];
  const float* in_b = (const float*)d_in[11];
  const float* lin_w = (const float*)d_in[12];
  const float* lin_b = (const float*)d_in[13];
  const float* cw1 = (const float*)d_in[14];
  const float* cb1 = (const float*)d_in[15];
  const float* cw2 = (const float*)d_in[16];
  const float* cb2 = (const float*)d_in[17];
  const float* ln_g = (const float*)d_in[18];
  const float* ln_b = (const float*)d_in[19];
  const float* pa_w1 = (const float*)d_in[20];
  const float* pa_b1 = (const float*)d_in[21];
  const float* pa_w2 = (const float*)d_in[22];
  const float* pa_b2 = (const float*)d_in[23];
  const float* hw1 = (const float*)d_in[24];
  const float* hb1 = (const float*)d_in[25];
  const float* hw2 = (const float*)d_in[26];
  const float* hb2 = (const float*)d_in[27];
  float* qout = (float*)d_out;

  char* w = (char*)d_ws;
  auto alloc = [&](size_t bytes) {
    char* p = w;
    w += (bytes + 255) & ~(size_t)255;
    return p;
  };
  __hip_bfloat16* t_e = (__hip_bfloat16*)alloc((size_t)EE * HH * 2);  // 164 MB
  float* h = (float*)alloc((size_t)NN * HH * 4);
  float* yzf = (float*)alloc((size_t)NN * HH * 4);  // z-accumulator
  __hip_bfloat16* hb = (__hip_bfloat16*)alloc((size_t)NN * HH * 2);
  __hip_bfloat16* t2 = (__hip_bfloat16*)alloc((size_t)NN * HH * 2);
  __hip_bfloat16* Wlt = (__hip_bfloat16*)alloc((size_t)LL * HH * HH * 2);
  float* bl = (float*)alloc((size_t)LL * HH * 4);
  __hip_bfloat16* cw1t = (__hip_bfloat16*)alloc((size_t)LL * HH * HH * 2);
  __hip_bfloat16* cw2t = (__hip_bfloat16*)alloc((size_t)LL * HH * HH * 2);
  __hip_bfloat16* paw1t = (__hip_bfloat16*)alloc((size_t)HH * HH * 2);
  float* scores = (float*)alloc((size_t)NN * 4);
  float* pmax = (float*)alloc(5008 * 4);
  float* en = (float*)alloc((size_t)NN * 4);
  float* seg = (float*)alloc((BBG + 1) * 4);
  float* gmax = (float*)alloc(4);
  float* pooled = (float*)alloc((size_t)BBG * HH * 4);
  int* cnt = (int*)alloc((size_t)NN * 4);
  int* rowptr = (int*)alloc((size_t)(NN + 1) * 4);
  int* cursor = (int*)alloc((size_t)NN * 4);
  int* posof = (int*)alloc((size_t)EE * 4);
  int* srcp = (int*)alloc((size_t)EE * 4);
  int* dstp = (int*)alloc((size_t)EE * 4);

  const int* esrc = edge_index;
  const int* edst = edge_index + EE;

  hipMemsetAsync(cnt, 0, (size_t)NN * 4, stream);
  hipMemsetAsync(seg, 0, (BBG + 1) * 4, stream);
  hipMemsetAsync(pooled, 0, (size_t)BBG * HH * 4, stream);

  // CSR build
  hist_k<<<(EE + 255) / 256, 256, 0, stream>>>(edst, cnt);
  scan_k<<<1, 256, 0, stream>>>(cnt, rowptr);
  hipMemcpyAsync(cursor, rowptr, (size_t)NN * 4, hipMemcpyDeviceToDevice, stream);
  scatter_k<<<(EE + 255) / 256, 256, 0, stream>>>(esrc, edst, cursor, posof,
                                                  srcp, dstp);

  fold_edge_w<<<LL * 256, 256, 0, stream>>>(ew2, lin_w, eb2, lin_b, Wlt, bl);
  tcast_all<<<3328, 256, 0, stream>>>(cw1, cw2, pa_w1, cw1t, cw2t, paw1t);
  edge_hidden<<<EE / 16, 256, 0, stream>>>(edge_attr, ew1, eb1, posof, t_e);
  node_init<<<NN / 16, 256, 0, stream>>>(x, cc, node_gid, node_lid, in_w, in_b,
                                         h, yzf, hb);

  dim3 gE(2, EE / 128), gN((NN + 127) / 128, 2);
  const int gMLP = (NN + 63) / 64;
  for (int l = 0; l < LL; l++) {
    edge_fused<<<gE, 256, 0, stream>>>(t_e, Wlt + (size_t)l * HH * HH,
                                       bl + l * HH, hb, srcp, dstp, yzf);
    mlp_ln<<<gMLP, 256, 0, stream>>>(
        yzf, cw1t + (size_t)l * HH * HH, cb1 + l * HH,
        cw2t + (size_t)l * HH * HH, cb2 + l * HH, ln_g + l * HH, ln_b + l * HH,
        h, yzf, hb);
  }

  gemm256<EPI_TANH><<<gN, 256, 0, stream>>>(hb, paw1t, pa_b1, NN, nullptr, t2);
  score_k<<<NN / 4, 256, 0, stream>>>(t2, pa_w2, pa_b2, scores, pmax);
  gmax_k<<<1, 256, 0, stream>>>(pmax, NN / 4, gmax);
  esum_k<<<(NN + 255) / 256, 256, 0, stream>>>(scores, node_gid, gmax, en, seg);
  pooled_k<<<BBG * 40, 256, 0, stream>>>(h, en, seg, pooled);
  head_k<<<BBG, 256, 0, stream>>>(pooled, hw1, hb1, hw2, hb2, qout);
}

// Round 12
// 1112.535 us; speedup vs baseline: 1.6252x; 1.0847x over previous
//
#include <hip/hip_runtime.h>
#include <hip/hip_bf16.h>
#include <cstdint>

// GraphQNet: N=20000 nodes, E=320000 edges, B=20 graphs (1000 each), H=256, L=6.
// R12: R11 + mlp_ln re-tiled to 32-row blocks (grid 625 vs 313). R11's mlp_ln
// was grid-starved: 313 blocks x 54KB LDS = 1.2 blocks/CU, half the CUs idle,
// 16 barriers unhidden. New mapping: wave = (row-tile w&1) x (col-half w>>1),
// acc 32 regs, LDS 34.6KB -> 4 blocks/CU at launch_bounds(256,4).
// edge_fused unchanged from R11 (98.8us, best measured).

#define NN 20000
#define EE 320000
#define BBG 20
#define PGN 1000
#define HH 256
#define LL 6

typedef short bf16x8 __attribute__((ext_vector_type(8)));
typedef float f32x4 __attribute__((ext_vector_type(4)));

__device__ __forceinline__ void async16(const void* g, void* l) {
  __builtin_amdgcn_global_load_lds(
      (const __attribute__((address_space(1))) unsigned int*)(uintptr_t)g,
      (__attribute__((address_space(3))) unsigned int*)(uintptr_t)l, 16, 0, 0);
}

__device__ __forceinline__ float siluf(float x) { return x / (1.f + __expf(-x)); }

__device__ __forceinline__ unsigned int f2bu(float x) {
  __hip_bfloat16 h = __float2bfloat16(x);
  return (unsigned int)*(unsigned short*)&h;
}

__device__ __forceinline__ float b2f(unsigned short u) {
  unsigned int v = ((unsigned int)u) << 16;
  return *(float*)&v;
}

enum { EPI_SILU = 1, EPI_PLAIN = 2, EPI_TANH = 3 };

// ---------------- node GEMM: C = A[M,256]@W^T (+bias) ----------------
template <int EPI>
__global__ void __launch_bounds__(256, 2) gemm256(
    const __hip_bfloat16* __restrict__ A, const __hip_bfloat16* __restrict__ Wt,
    const float* __restrict__ bias, int M, float* __restrict__ outf,
    __hip_bfloat16* __restrict__ outb) {
  __shared__ __align__(16) __hip_bfloat16 sA[128 * 32];
  __shared__ __align__(16) __hip_bfloat16 sB[128 * 32];

  const int t = threadIdx.x;
  const int wave = t >> 6, lane = t & 63;
  const int row0 = blockIdx.x * 128;
  const int col0 = blockIdx.y * 128;

  const int wrow = (wave >> 1) * 64;
  const int wcol = (wave & 1) * 64;
  const int fr = lane & 15, q = lane >> 4;

  f32x4 zero = {0.f, 0.f, 0.f, 0.f};
  f32x4 acc[4][4];
#pragma unroll
  for (int i = 0; i < 4; i++)
#pragma unroll
    for (int j = 0; j < 4; j++) acc[i][j] = zero;

  const int c1 = t, c2 = t + 256;
  const int lr1 = c1 >> 2, lr2 = c2 >> 2;
  const int q1 = (c1 & 3) ^ ((lr1 >> 1) & 3);
  const int q2 = (c2 & 3) ^ ((lr2 >> 1) & 3);
  int rA1 = row0 + lr1; if (rA1 >= M) rA1 = M - 1;
  int rA2 = row0 + lr2; if (rA2 >= M) rA2 = M - 1;
  const int rB1 = col0 + lr1, rB2 = col0 + lr2;

  for (int k0 = 0; k0 < 256; k0 += 32) {
    async16((const char*)(A + (size_t)rA1 * HH + k0) + q1 * 16,
            (char*)sA + wave * 1024);
    async16((const char*)(A + (size_t)rA2 * HH + k0) + q2 * 16,
            (char*)sA + 4096 + wave * 1024);
    async16((const char*)(Wt + (size_t)rB1 * HH + k0) + q1 * 16,
            (char*)sB + wave * 1024);
    async16((const char*)(Wt + (size_t)rB2 * HH + k0) + q2 * 16,
            (char*)sB + 4096 + wave * 1024);
    __syncthreads();
    bf16x8 af[4], bfr[4];
#pragma unroll
    for (int i = 0; i < 4; i++) {
      const int row = wrow + i * 16 + fr;
      af[i] = *(const bf16x8*)&sA[row * 32 + ((q ^ ((row >> 1) & 3))) * 8];
    }
#pragma unroll
    for (int j = 0; j < 4; j++) {
      const int row = wcol + j * 16 + fr;
      bfr[j] = *(const bf16x8*)&sB[row * 32 + ((q ^ ((row >> 1) & 3))) * 8];
    }
#pragma unroll
    for (int i = 0; i < 4; i++)
#pragma unroll
      for (int j = 0; j < 4; j++)
        acc[i][j] = __builtin_amdgcn_mfma_f32_16x16x32_bf16(af[i], bfr[j],
                                                            acc[i][j], 0, 0, 0);
    __syncthreads();
  }

  // C/D layout: col = lane&15, row = (lane>>4)*4 + reg  [m89-verified]
#pragma unroll
  for (int j = 0; j < 4; j++) {
    const int col = col0 + wcol + j * 16 + fr;
    const float bs = bias[col];
#pragma unroll
    for (int i = 0; i < 4; i++) {
      const int lr0 = wrow + i * 16 + q * 4;
#pragma unroll
      for (int r = 0; r < 4; r++) {
        const int grow = row0 + lr0 + r;
        float v = acc[i][j][r] + bs;
        if (grow < M) {
          if (EPI == EPI_SILU) {
            outb[(size_t)grow * HH + col] = __float2bfloat16(siluf(v));
          } else if (EPI == EPI_PLAIN) {
            outf[(size_t)grow * HH + col] = v;
          } else {
            outb[(size_t)grow * HH + col] = __float2bfloat16(tanhf(v));
          }
        }
      }
    }
  }
}

// ---- fused node MLP + LN + residual (R12: 32 rows/block, grid 625) ----
// Wave w: row-tile rt=w&1 (16 rows), col-half ch=w>>1 (128 cols). acc = 8 f32x4.
// t2 = silu(z@W1^T+b1) -> sT bf16 [32][264]; y = t2@W2^T+b2 -> sT;
// h += silu(LN(y)); yzf = h; hb = bf16(h). t2/y never touch HBM.
__global__ void __launch_bounds__(256, 4) mlp_ln(
    const float* __restrict__ z, const __hip_bfloat16* __restrict__ W1t,
    const float* __restrict__ b1, const __hip_bfloat16* __restrict__ W2t,
    const float* __restrict__ b2, const float* __restrict__ g,
    const float* __restrict__ bbv, float* __restrict__ h,
    float* __restrict__ yzf, __hip_bfloat16* __restrict__ hb) {
  __shared__ __align__(16) char smem[2048 + 16384 + 32 * 264 * 2];
  __hip_bfloat16* sA = (__hip_bfloat16*)smem;              // [32][32]  2KB
  __hip_bfloat16* sB = (__hip_bfloat16*)(smem + 2048);     // [256][32] 16KB
  unsigned short* sT = (unsigned short*)(smem + 18432);    // [32][264] bf16

  const int t = threadIdx.x;
  const int wave = t >> 6, lane = t & 63;
  const int row0 = blockIdx.x * 32;  // 625 * 32 = 20000 exactly
  const int fr = lane & 15, q = lane >> 4;
  const int rt = wave & 1;           // row-tile (16 rows)
  const int chf = wave >> 1;         // col-half (128 cols)

  // A staging (phase 1, fp32 z): 128 chunks = [32 rows][4 slots]; thread t<128.
  const int lrA = t >> 2;
  const int qA = (t & 3) ^ ((lrA >> 1) & 3);
  // B staging: 1024 chunks; thread t stages chunks t + p*256.
  int qB[4], rB[4];
#pragma unroll
  for (int p = 0; p < 4; p++) {
    const int c = t + p * 256;
    const int lr = c >> 2;
    qB[p] = (c & 3) ^ ((lr >> 1) & 3);
    rB[p] = lr;
  }

  f32x4 zero = {0.f, 0.f, 0.f, 0.f};
  f32x4 acc[8];
#pragma unroll
  for (int j = 0; j < 8; j++) acc[j] = zero;

  const int arow = rt * 16 + fr;                      // A-fragment row (local)
  const int aswz = (q ^ ((arow >> 1) & 3)) * 8;

  // -------- phase 1: z @ W1^T --------
  for (int k0 = 0; k0 < 256; k0 += 32) {
    if (t < 128) {
      const float* s1 = z + (size_t)(row0 + lrA) * HH + k0 + qA * 8;
      float4 a0 = *(const float4*)s1;
      float4 a1 = *(const float4*)(s1 + 4);
      uint4 u;
      u.x = f2bu(a0.x) | (f2bu(a0.y) << 16);
      u.y = f2bu(a0.z) | (f2bu(a0.w) << 16);
      u.z = f2bu(a1.x) | (f2bu(a1.y) << 16);
      u.w = f2bu(a1.z) | (f2bu(a1.w) << 16);
      *(uint4*)((char*)sA + t * 16) = u;
    }
#pragma unroll
    for (int p = 0; p < 4; p++)
      async16((const char*)(W1t + (size_t)rB[p] * HH + k0) + qB[p] * 16,
              (char*)sB + p * 4096 + wave * 1024);
    __syncthreads();
    bf16x8 af = *(const bf16x8*)&sA[arow * 32 + aswz];
#pragma unroll
    for (int j = 0; j < 8; j++) {
      const int row = chf * 128 + j * 16 + fr;
      bf16x8 bfr = *(const bf16x8*)&sB[row * 32 + ((q ^ ((row >> 1) & 3))) * 8];
      acc[j] = __builtin_amdgcn_mfma_f32_16x16x32_bf16(af, bfr, acc[j], 0, 0, 0);
    }
    __syncthreads();
  }
  // t2 = silu(acc + b1) -> sT  (C layout: col=fr, row=q*4+r within tile)
#pragma unroll
  for (int j = 0; j < 8; j++) {
    const int col = chf * 128 + j * 16 + fr;
    const float bs = b1[col];
    const int r0 = rt * 16 + q * 4;
#pragma unroll
    for (int r = 0; r < 4; r++)
      sT[(r0 + r) * 264 + col] = (unsigned short)f2bu(siluf(acc[j][r] + bs));
  }
#pragma unroll
  for (int j = 0; j < 8; j++) acc[j] = zero;

  // -------- phase 2: t2 @ W2^T (A from sT) --------
  for (int k0 = 0; k0 < 256; k0 += 32) {
#pragma unroll
    for (int p = 0; p < 4; p++)
      async16((const char*)(W2t + (size_t)rB[p] * HH + k0) + qB[p] * 16,
              (char*)sB + p * 4096 + wave * 1024);
    __syncthreads();  // orders sT writes (phase-1 epilogue) before reads
    bf16x8 af = *(const bf16x8*)&sT[arow * 264 + k0 + q * 8];
#pragma unroll
    for (int j = 0; j < 8; j++) {
      const int row = chf * 128 + j * 16 + fr;
      bf16x8 bfr = *(const bf16x8*)&sB[row * 32 + ((q ^ ((row >> 1) & 3))) * 8];
      acc[j] = __builtin_amdgcn_mfma_f32_16x16x32_bf16(af, bfr, acc[j], 0, 0, 0);
    }
    __syncthreads();
  }
  // y = acc + b2 -> sT (overwrite; trailing barrier above ordered the reads)
#pragma unroll
  for (int j = 0; j < 8; j++) {
    const int col = chf * 128 + j * 16 + fr;
    const float bs = b2[col];
    const int r0 = rt * 16 + q * 4;
#pragma unroll
    for (int r = 0; r < 4; r++)
      sT[(r0 + r) * 264 + col] = (unsigned short)f2bu(acc[j][r] + bs);
  }
  __syncthreads();

  // LN + silu + residual: wave handles rows wave*8 .. +8
  for (int rr = 0; rr < 8; rr++) {
    const int r = wave * 8 + rr;
    const int grow = row0 + r;
    float v[4];
    float s = 0.f;
#pragma unroll
    for (int i = 0; i < 4; i++) {
      v[i] = b2f(sT[r * 264 + lane + i * 64]);
      s += v[i];
    }
#pragma unroll
    for (int o = 32; o; o >>= 1) s += __shfl_xor(s, o);
    const float mean = s * (1.f / 256.f);
    float var = 0.f;
#pragma unroll
    for (int i = 0; i < 4; i++) { float d = v[i] - mean; var += d * d; }
#pragma unroll
    for (int o = 32; o; o >>= 1) var += __shfl_xor(var, o);
    const float rs = rsqrtf(var * (1.f / 256.f) + 1e-5f);
#pragma unroll
    for (int i = 0; i < 4; i++) {
      const int c = lane + i * 64;
      float ln = (v[i] - mean) * rs * g[c] + bbv[c];
      float si = siluf(ln);
      size_t idx = (size_t)grow * HH + c;
      float nh = h[idx] + si;
      h[idx] = nh;
      yzf[idx] = nh;
      hb[idx] = __float2bfloat16(nh);
    }
  }
}

// -------- fused edge GEMM + segmented reduce (unchanged from R11) -----------
__global__ void __launch_bounds__(256, 4) edge_fused(
    const __hip_bfloat16* __restrict__ te, const __hip_bfloat16* __restrict__ Wt,
    const float* __restrict__ bias, const __hip_bfloat16* __restrict__ hbv,
    const int* __restrict__ srcp, const int* __restrict__ dstp,
    float* __restrict__ z) {
  __shared__ __align__(16) char smem[32768];  // sA 2x8KB | sB 2x8KB
  __shared__ int sSrc[128], sDst[128];
  __hip_bfloat16* sA = (__hip_bfloat16*)smem;
  __hip_bfloat16* sB = (__hip_bfloat16*)(smem + 16384);
  unsigned short* sRed = (unsigned short*)smem;  // [64][130] (epilogue union)

  const int t = threadIdx.x;
  const int wave = t >> 6, lane = t & 63;
  const int row0 = blockIdx.y * 128;
  const int col0 = blockIdx.x * 128;

  if (t < 128) { sSrc[t] = srcp[row0 + t]; sDst[t] = dstp[row0 + t]; }
  __syncthreads();

  const int wrow = (wave >> 1) * 64;
  const int fr = lane & 15, q = lane >> 4;
  const int rc = lane, rb = wave;  // reduce identity

  f32x4 zero = {0.f, 0.f, 0.f, 0.f};
  f32x4 acc[4][4];
#pragma unroll
  for (int i = 0; i < 4; i++)
#pragma unroll
    for (int j = 0; j < 4; j++) acc[i][j] = zero;

  const int c1 = t, c2 = t + 256;
  const int lr1 = c1 >> 2, lr2 = c2 >> 2;
  const int q1 = (c1 & 3) ^ ((lr1 >> 1) & 3);
  const int q2 = (c2 & 3) ^ ((lr2 >> 1) & 3);
  const int rA1 = row0 + lr1, rA2 = row0 + lr2;
  const int rB1 = col0 + lr1, rB2 = col0 + lr2;

#pragma unroll
  for (int it = 0; it < 4; it++) {
    const int ka = it * 64, kb = ka + 32;
    async16((const char*)(te + (size_t)rA1 * HH + ka) + q1 * 16,
            (char*)sA + wave * 1024);
    async16((const char*)(te + (size_t)rA2 * HH + ka) + q2 * 16,
            (char*)sA + 4096 + wave * 1024);
    async16((const char*)(te + (size_t)rA1 * HH + kb) + q1 * 16,
            (char*)sA + 8192 + wave * 1024);
    async16((const char*)(te + (size_t)rA2 * HH + kb) + q2 * 16,
            (char*)sA + 12288 + wave * 1024);
    async16((const char*)(Wt + (size_t)rB1 * HH + ka) + q1 * 16,
            (char*)sB + wave * 1024);
    async16((const char*)(Wt + (size_t)rB2 * HH + ka) + q2 * 16,
            (char*)sB + 4096 + wave * 1024);
    async16((const char*)(Wt + (size_t)rB1 * HH + kb) + q1 * 16,
            (char*)sB + 8192 + wave * 1024);
    async16((const char*)(Wt + (size_t)rB2 * HH + kb) + q2 * 16,
            (char*)sB + 12288 + wave * 1024);
    __syncthreads();
#pragma unroll
    for (int half = 0; half < 2; half++) {
      const __hip_bfloat16* pA = sA + half * 4096;
      const __hip_bfloat16* pB = sB + half * 4096;
      bf16x8 af[4], bfr[4];
#pragma unroll
      for (int i = 0; i < 4; i++) {
        const int row = wrow + i * 16 + fr;
        af[i] = *(const bf16x8*)&pA[row * 32 + ((q ^ ((row >> 1) & 3))) * 8];
      }
#pragma unroll
      for (int j = 0; j < 4; j++) {
        const int row = (wave & 1) * 64 + j * 16 + fr;
        bfr[j] = *(const bf16x8*)&pB[row * 32 + ((q ^ ((row >> 1) & 3))) * 8];
      }
#pragma unroll
      for (int i = 0; i < 4; i++)
#pragma unroll
        for (int j = 0; j < 4; j++)
          acc[i][j] = __builtin_amdgcn_mfma_f32_16x16x32_bf16(af[i], bfr[j],
                                                              acc[i][j], 0, 0, 0);
    }
    __syncthreads();
  }

  // epilogue: two 64-col halves staged bf16 in sRed; gathers in 8-reg chunks
#pragma unroll
  for (int hf = 0; hf < 2; hf++) {
    if ((wave & 1) == hf) {
#pragma unroll
      for (int j = 0; j < 4; j++) {
        const int cl = j * 16 + fr;
        const float bs = bias[col0 + hf * 64 + cl];
#pragma unroll
        for (int i = 0; i < 4; i++) {
          const int r0 = wrow + i * 16 + q * 4;
          f32x4 v = acc[i][j];
          unsigned int p0 = f2bu(v[0] + bs) | (f2bu(v[1] + bs) << 16);
          unsigned int p1 = f2bu(v[2] + bs) | (f2bu(v[3] + bs) << 16);
          *(unsigned int*)&sRed[cl * 130 + r0] = p0;
          *(unsigned int*)&sRed[cl * 130 + r0 + 2] = p1;
        }
      }
    }
    __syncthreads();
    const int gcol = col0 + hf * 64 + rc;
    float a = 0.f;
    int cur = sDst[rb * 32];
    for (int ch = 0; ch < 4; ch++) {
      float hv8[8];
#pragma unroll
      for (int u = 0; u < 8; u++)
        hv8[u] = __bfloat162float(
            hbv[(size_t)sSrc[rb * 32 + ch * 8 + u] * HH + gcol]);
#pragma unroll
      for (int u = 0; u < 8; u++) {
        const int row = rb * 32 + ch * 8 + u;
        const int d = sDst[row];
        if (d != cur) {
          unsafeAtomicAdd(&z[(size_t)cur * HH + gcol], a);
          a = 0.f;
          cur = d;
        }
        float m = b2f(sRed[rc * 130 + row]) + hv8[u];
        a += m > 0.f ? m : 0.f;
      }
    }
    unsafeAtomicAdd(&z[(size_t)cur * HH + gcol], a);
    __syncthreads();
  }
}

// ---- CSR build (per-launch; edge_index is a fixed input) ----
__global__ void __launch_bounds__(256) hist_k(const int* __restrict__ edst,
                                              int* __restrict__ cnt) {
  const int e = blockIdx.x * 256 + threadIdx.x;
  if (e < EE) atomicAdd(&cnt[edst[e]], 1);
}

// wave-shuffle scan: 2 barriers per 256-chunk
__global__ void __launch_bounds__(256) scan_k(const int* __restrict__ cnt,
                                              int* __restrict__ rowptr) {
  __shared__ int wsum[4];
  __shared__ int carry;
  const int t = threadIdx.x, wave = t >> 6, lane = t & 63;
  if (t == 0) carry = 0;
  __syncthreads();
  for (int base = 0; base < NN; base += 256) {
    const int idx = base + t;
    int v = (idx < NN) ? cnt[idx] : 0;
    int inc = v;
#pragma unroll
    for (int o = 1; o < 64; o <<= 1) {
      int u = __shfl_up(inc, o);
      if (lane >= o) inc += u;
    }
    if (lane == 63) wsum[wave] = inc;
    __syncthreads();
    int woff = 0;
    for (int w2 = 0; w2 < wave; w2++) woff += wsum[w2];
    if (idx < NN) rowptr[idx] = carry + woff + inc - v;
    const int total = wsum[0] + wsum[1] + wsum[2] + wsum[3];
    __syncthreads();
    if (t == 0) carry += total;
    __syncthreads();
  }
  if (t == 0) rowptr[NN] = carry;
}

__global__ void __launch_bounds__(256) scatter_k(
    const int* __restrict__ esrc, const int* __restrict__ edst,
    int* __restrict__ cursor, int* __restrict__ posof,
    int* __restrict__ srcp, int* __restrict__ dstp) {
  const int e = blockIdx.x * 256 + threadIdx.x;
  if (e < EE) {
    const int d = edst[e];
    const int pos = atomicAdd(&cursor[d], 1);
    posof[e] = pos;
    srcp[pos] = esrc[e];
    dstp[pos] = d;
  }
}

// t_e[posof[e]] = relu(ea[e] @ ew1 + eb1) -> bf16 (dst-sorted order)
__global__ void __launch_bounds__(256) edge_hidden(
    const float* __restrict__ ea, const float* __restrict__ ew1,
    const float* __restrict__ eb1, const int* __restrict__ posof,
    __hip_bfloat16* __restrict__ tout) {
  __shared__ float w[8 * 256];
  __shared__ float b[256];
  __shared__ float sea[16 * 8];
  __shared__ int spos[16];
  const int t = threadIdx.x;
  for (int i = t; i < 8 * 256; i += 256) w[i] = ew1[i];
  b[t] = eb1[t];
  const int e0 = blockIdx.x * 16;
  if (t < 128) sea[t] = ea[(size_t)e0 * 8 + t];
  if (t < 16) spos[t] = posof[e0 + t];
  __syncthreads();
  for (int e = 0; e < 16; e++) {
    float a = b[t];
#pragma unroll
    for (int j = 0; j < 8; j++) a += sea[e * 8 + j] * w[j * 256 + t];
    tout[(size_t)spos[e] * HH + t] = __float2bfloat16(a > 0.f ? a : 0.f);
  }
}

// W_l = ew2 @ lin_w[l] (store transposed bf16), b_l = eb2 @ lin_w[l] + lin_b[l]
__global__ void __launch_bounds__(256) fold_edge_w(
    const float* __restrict__ ew2, const float* __restrict__ lin_w,
    const float* __restrict__ eb2, const float* __restrict__ lin_b,
    __hip_bfloat16* __restrict__ Wlt, float* __restrict__ bl) {
  const int l = blockIdx.x >> 8, j = blockIdx.x & 255;
  const int c = threadIdx.x;
  __shared__ float row[256];
  row[c] = ew2[j * 256 + c];
  __syncthreads();
  const float* lw = lin_w + (size_t)l * 65536;
  float a = 0.f;
  for (int k = 0; k < 256; k++) a += row[k] * lw[k * 256 + c];
  Wlt[((size_t)l * 256 + c) * 256 + j] = __float2bfloat16(a);
  if (j == 0) {
    float s = lin_b[l * 256 + c];
    for (int k = 0; k < 256; k++) s += eb2[k] * lw[k * 256 + c];
    bl[l * 256 + c] = s;
  }
}

// transpose+cast fp32 [256,256] -> bf16^T for cw1(6), cw2(6), pa_w1(1)
__global__ void __launch_bounds__(256) tcast_all(
    const float* __restrict__ cw1, const float* __restrict__ cw2,
    const float* __restrict__ paw1, __hip_bfloat16* __restrict__ cw1t,
    __hip_bfloat16* __restrict__ cw2t, __hip_bfloat16* __restrict__ paw1t) {
  const int b = blockIdx.x;
  const float* s;
  __hip_bfloat16* d;
  if (b < 1536) { int l = b >> 8; s = cw1 + (size_t)l * 65536; d = cw1t + (size_t)l * 65536; }
  else if (b < 3072) { int l = (b - 1536) >> 8; s = cw2 + (size_t)l * 65536; d = cw2t + (size_t)l * 65536; }
  else { s = paw1; d = paw1t; }
  const int r = b & 255, c = threadIdx.x;
  d[(size_t)c * 256 + r] = __float2bfloat16(s[(size_t)r * 256 + c]);
}

// h = silu([x, c_scalar] @ in_w + in_b); yzf = h; hb = bf16(h)
__global__ void __launch_bounds__(256) node_init(
    const float* __restrict__ x, const float* __restrict__ cc,
    const int* __restrict__ gid, const int* __restrict__ lid,
    const float* __restrict__ in_w, const float* __restrict__ in_b,
    float* __restrict__ h, float* __restrict__ yzf,
    __hip_bfloat16* __restrict__ hb) {
  __shared__ float w[17 * 256];
  __shared__ float b[256];
  __shared__ float sx[16 * 17];
  const int t = threadIdx.x;
  for (int i = t; i < 17 * 256; i += 256) w[i] = in_w[i];
  b[t] = in_b[t];
  const int n0 = blockIdx.x * 16;
  sx[(t >> 4) * 17 + (t & 15)] = x[(size_t)(n0 + (t >> 4)) * 16 + (t & 15)];
  if (t < 16) {
    int n = n0 + t;
    sx[t * 17 + 16] = cc[gid[n] * PGN + lid[n]];
  }
  __syncthreads();
  for (int e = 0; e < 16; e++) {
    float a = b[t];
#pragma unroll
    for (int j = 0; j < 17; j++) a += sx[e * 17 + j] * w[j * 256 + t];
    float s = siluf(a);
    size_t idx = (size_t)(n0 + e) * HH + t;
    h[idx] = s;
    yzf[idx] = s;
    hb[idx] = __float2bfloat16(s);
  }
}

// scores[n] = s1[n,:] . pa_w2 + pa_b2 ; per-block max -> pmax
__global__ void __launch_bounds__(256) score_k(
    const __hip_bfloat16* __restrict__ s1, const float* __restrict__ pw2,
    const float* __restrict__ pb2, float* __restrict__ scores,
    float* __restrict__ pmax) {
  __shared__ float w2[256];
  __shared__ float bm[4];
  const int t = threadIdx.x, wave = t >> 6, lane = t & 63;
  w2[t] = pw2[t];
  __syncthreads();
  const size_t row = (size_t)blockIdx.x * 4 + wave;
  float a = 0.f;
#pragma unroll
  for (int i = 0; i < 4; i++) {
    int c = lane + i * 64;
    a += __bfloat162float(s1[row * HH + c]) * w2[c];
  }
#pragma unroll
  for (int o = 32; o; o >>= 1) a += __shfl_xor(a, o);
  float sc = a + pb2[0];
  if (lane == 0) { scores[row] = sc; bm[wave] = sc; }
  __syncthreads();
  if (t == 0) pmax[blockIdx.x] = fmaxf(fmaxf(bm[0], bm[1]), fmaxf(bm[2], bm[3]));
}

__global__ void __launch_bounds__(256) gmax_k(const float* __restrict__ pmax,
                                              int n, float* __restrict__ gmax) {
  const int t = threadIdx.x;
  float m = -3.4e38f;
  for (int i = t; i < n; i += 256) m = fmaxf(m, pmax[i]);
#pragma unroll
  for (int o = 32; o; o >>= 1) m = fmaxf(m, __shfl_xor(m, o));
  __shared__ float wm[4];
  if ((t & 63) == 0) wm[t >> 6] = m;
  __syncthreads();
  if (t == 0) gmax[0] = fmaxf(fmaxf(wm[0], wm[1]), fmaxf(wm[2], wm[3]));
}

// en = exp(s - gmax); seg[g] += en ; seg[BBG] = total
__global__ void __launch_bounds__(256) esum_k(
    const float* __restrict__ scores, const int* __restrict__ gid,
    const float* __restrict__ gmax, float* __restrict__ en,
    float* __restrict__ seg) {
  __shared__ float ls[BBG + 1];
  const int t = threadIdx.x;
  if (t < BBG + 1) ls[t] = 0.f;
  __syncthreads();
  const int n = blockIdx.x * 256 + t;
  if (n < NN) {
    float e = __expf(scores[n] - gmax[0]);
    en[n] = e;
    atomicAdd(&ls[gid[n]], e);
    atomicAdd(&ls[BBG], e);
  }
  __syncthreads();
  if (t < BBG + 1) unsafeAtomicAdd(&seg[t], ls[t]);
}

// pooled[g,:] = sum_n en[n]*h[n,:] / (seg[g] + 1e-8*total)
__global__ void __launch_bounds__(256) pooled_k(
    const float* __restrict__ h, const float* __restrict__ en,
    const float* __restrict__ seg, float* __restrict__ pooled) {
  const int g = blockIdx.x / 40, ch = blockIdx.x % 40;
  const int c = threadIdx.x;
  const int n0 = g * PGN + ch * 25;
  float a = 0.f;
  for (int i = 0; i < 25; i++) {
    int n = n0 + i;
    a += en[n] * h[(size_t)n * HH + c];
  }
  const float inv = 1.f / (seg[g] + 1e-8f * seg[BBG]);
  unsafeAtomicAdd(&pooled[g * HH + c], a * inv);
}

// q[b] = silu(pooled[b] @ hw1 + hb1) . hw2 + hb2
__global__ void __launch_bounds__(256) head_k(
    const float* __restrict__ pooled, const float* __restrict__ hw1,
    const float* __restrict__ hb1, const float* __restrict__ hw2,
    const float* __restrict__ hb2, float* __restrict__ qout) {
  const int b = blockIdx.x, c = threadIdx.x;
  __shared__ float p[256];
  __shared__ float wsum[4];
  p[c] = pooled[b * 256 + c];
  __syncthreads();
  float a = hb1[c];
  for (int k = 0; k < 256; k++) a += p[k] * hw1[k * 256 + c];
  float v = siluf(a) * hw2[c];
#pragma unroll
  for (int o = 32; o; o >>= 1) v += __shfl_xor(v, o);
  if ((c & 63) == 0) wsum[c >> 6] = v;
  __syncthreads();
  if (c == 0) qout[b] = wsum[0] + wsum[1] + wsum[2] + wsum[3] + hb2[0];
}

extern "C" void kernel_launch(void* const* d_in, const int* in_sizes, int n_in,
                              void* d_out, int out_size, void* d_ws, size_t ws_size,
                              hipStream_t stream) {
  const float* x = (const float*)d_in[0];
  const float* edge_attr = (const float*)d_in[1];
  const float* cc = (const float*)d_in[2];
  const int* edge_index = (const int*)d_in[3];
  const int* node_gid = (const int*)d_in[4];
  const int* node_lid = (const int*)d_in[5];
  const float* ew1 = (const float*)d_in[6];
  const float* eb1 = (const float*)d_in[7];
  const float* ew2 = (const float*)d_in[8];
  const float* eb2 = (const float*)d_in[9];
  const float* in_w = (const float*)d_in[10];
  const float* in_b = (const float*)d_in[11];
  const float* lin_w = (const float*)d_in[12];
  const float* lin_b = (const float*)d_in[13];
  const float* cw1 = (const float*)d_in[14];
  const float* cb1 = (const float*)d_in[15];
  const float* cw2 = (const float*)d_in[16];
  const float* cb2 = (const float*)d_in[17];
  const float* ln_g = (const float*)d_in[18];
  const float* ln_b = (const float*)d_in[19];
  const float* pa_w1 = (const float*)d_in[20];
  const float* pa_b1 = (const float*)d_in[21];
  const float* pa_w2 = (const float*)d_in[22];
  const float* pa_b2 = (const float*)d_in[23];
  const float* hw1 = (const float*)d_in[24];
  const float* hb1 = (const float*)d_in[25];
  const float* hw2 = (const float*)d_in[26];
  const float* hb2 = (const float*)d_in[27];
  float* qout = (float*)d_out;

  char* w = (char*)d_ws;
  auto alloc = [&](size_t bytes) {
    char* p = w;
    w += (bytes + 255) & ~(size_t)255;
    return p;
  };
  __hip_bfloat16* t_e = (__hip_bfloat16*)alloc((size_t)EE * HH * 2);  // 164 MB
  float* h = (float*)alloc((size_t)NN * HH * 4);
  float* yzf = (float*)alloc((size_t)NN * HH * 4);  // z-accumulator
  __hip_bfloat16* hb = (__hip_bfloat16*)alloc((size_t)NN * HH * 2);
  __hip_bfloat16* t2 = (__hip_bfloat16*)alloc((size_t)NN * HH * 2);
  __hip_bfloat16* Wlt = (__hip_bfloat16*)alloc((size_t)LL * HH * HH * 2);
  float* bl = (float*)alloc((size_t)LL * HH * 4);
  __hip_bfloat16* cw1t = (__hip_bfloat16*)alloc((size_t)LL * HH * HH * 2);
  __hip_bfloat16* cw2t = (__hip_bfloat16*)alloc((size_t)LL * HH * HH * 2);
  __hip_bfloat16* paw1t = (__hip_bfloat16*)alloc((size_t)HH * HH * 2);
  float* scores = (float*)alloc((size_t)NN * 4);
  float* pmax = (float*)alloc(5008 * 4);
  float* en = (float*)alloc((size_t)NN * 4);
  float* seg = (float*)alloc((BBG + 1) * 4);
  float* gmax = (float*)alloc(4);
  float* pooled = (float*)alloc((size_t)BBG * HH * 4);
  int* cnt = (int*)alloc((size_t)NN * 4);
  int* rowptr = (int*)alloc((size_t)(NN + 1) * 4);
  int* cursor = (int*)alloc((size_t)NN * 4);
  int* posof = (int*)alloc((size_t)EE * 4);
  int* srcp = (int*)alloc((size_t)EE * 4);
  int* dstp = (int*)alloc((size_t)EE * 4);

  const int* esrc = edge_index;
  const int* edst = edge_index + EE;

  hipMemsetAsync(cnt, 0, (size_t)NN * 4, stream);
  hipMemsetAsync(seg, 0, (BBG + 1) * 4, stream);
  hipMemsetAsync(pooled, 0, (size_t)BBG * HH * 4, stream);

  // CSR build
  hist_k<<<(EE + 255) / 256, 256, 0, stream>>>(edst, cnt);
  scan_k<<<1, 256, 0, stream>>>(cnt, rowptr);
  hipMemcpyAsync(cursor, rowptr, (size_t)NN * 4, hipMemcpyDeviceToDevice, stream);
  scatter_k<<<(EE + 255) / 256, 256, 0, stream>>>(esrc, edst, cursor, posof,
                                                  srcp, dstp);

  fold_edge_w<<<LL * 256, 256, 0, stream>>>(ew2, lin_w, eb2, lin_b, Wlt, bl);
  tcast_all<<<3328, 256, 0, stream>>>(cw1, cw2, pa_w1, cw1t, cw2t, paw1t);
  edge_hidden<<<EE / 16, 256, 0, stream>>>(edge_attr, ew1, eb1, posof, t_e);
  node_init<<<NN / 16, 256, 0, stream>>>(x, cc, node_gid, node_lid, in_w, in_b,
                                         h, yzf, hb);

  dim3 gE(2, EE / 128), gN((NN + 127) / 128, 2);
  const int gMLP = NN / 32;  // 625
  for (int l = 0; l < LL; l++) {
    edge_fused<<<gE, 256, 0, stream>>>(t_e, Wlt + (size_t)l * HH * HH,
                                       bl + l * HH, hb, srcp, dstp, yzf);
    mlp_ln<<<gMLP, 256, 0, stream>>>(
        yzf, cw1t + (size_t)l * HH * HH, cb1 + l * HH,
        cw2t + (size_t)l * HH * HH, cb2 + l * HH, ln_g + l * HH, ln_b + l * HH,
        h, yzf, hb);
  }

  gemm256<EPI_TANH><<<gN, 256, 0, stream>>>(hb, paw1t, pa_b1, NN, nullptr, t2);
  score_k<<<NN / 4, 256, 0, stream>>>(t2, pa_w2, pa_b2, scores, pmax);
  gmax_k<<<1, 256, 0, stream>>>(pmax, NN / 4, gmax);
  esum_k<<<(NN + 255) / 256, 256, 0, stream>>>(scores, node_gid, gmax, en, seg);
  pooled_k<<<BBG * 40, 256, 0, stream>>>(h, en, seg, pooled);
  head_k<<<BBG, 256, 0, stream>>>(pooled, hw1, hb1, hw2, hb2, qout);
}